// Round 2
// baseline (1096.586 us; speedup 1.0000x reference)
//
#include <hip/hip_runtime.h>
#include <hip/hip_bf16.h>

// Problem constants (fixed by the reference harness)
#define N_NODES 32768
#define N_EDGES 524288
#define NGRAPH  256
#define NPG     128
#define F_IN    64
#define F1      128
#define F2      64
#define F3      32
#define TN      16
#define BINS    16

// ---------------- degree ----------------
__global__ void deg_init(int* __restrict__ deg) {
    int i = blockIdx.x * 256 + threadIdx.x;
    if (i < N_NODES) deg[i] = 1;   // self loop
}
__global__ void deg_accum(const int* __restrict__ dst, int* __restrict__ deg) {
    int e = blockIdx.x * 256 + threadIdx.x;
    if (e < N_EDGES) atomicAdd(&deg[dst[e]], 1);
}
__global__ void deg_fin(const int* __restrict__ deg, float* __restrict__ dinv) {
    int i = blockIdx.x * 256 + threadIdx.x;
    if (i < N_NODES) dinv[i] = rsqrtf((float)deg[i]);
}

// ---------------- dense matmul: out[N,FOUT] = x[N,FIN] @ W[FIN,FOUT] ----------------
template<int FIN, int FOUT>
__global__ __launch_bounds__(256) void mm_kernel(const float* __restrict__ x,
                                                 const float* __restrict__ W,
                                                 float* __restrict__ out) {
    constexpr int ROWS = 256 / FOUT;
    __shared__ float xs[ROWS * FIN];
    int n0 = blockIdx.x * ROWS;
    for (int i = threadIdx.x; i < ROWS * FIN; i += 256) xs[i] = x[n0 * FIN + i];
    __syncthreads();
    int r = threadIdx.x / FOUT;
    int c = threadIdx.x % FOUT;
    float acc = 0.f;
#pragma unroll
    for (int k = 0; k < FIN; ++k) acc += xs[r * FIN + k] * W[k * FOUT + c];
    out[(n0 + r) * FOUT + c] = acc;
}

// ---------------- GCN aggregate: self-loop init (+bias), edge scatter, relu ----------------
template<int FOUT>
__global__ __launch_bounds__(256) void agg_init(const float* __restrict__ h,
                                                const float* __restrict__ dinv,
                                                const float* __restrict__ bias,
                                                float* __restrict__ out) {
    int idx = blockIdx.x * 256 + threadIdx.x;   // over N*FOUT
    int n = idx / FOUT, c = idx % FOUT;
    float di = dinv[n];
    out[idx] = di * di * h[idx] + bias[c];
}

template<int FOUT>
__global__ __launch_bounds__(256) void agg_edge(const int* __restrict__ src,
                                                const int* __restrict__ dst,
                                                const float* __restrict__ h,
                                                const float* __restrict__ dinv,
                                                float* __restrict__ out) {
    int idx = blockIdx.x * 256 + threadIdx.x;   // over E*FOUT (< 2^27)
    int e = idx / FOUT, c = idx % FOUT;
    int s = src[e], d = dst[e];
    float nrm = dinv[s] * dinv[d];
    atomicAdd(&out[d * FOUT + c], nrm * h[s * FOUT + c]);
}

__global__ void relu_k(float* __restrict__ x, int n) {
    int i = blockIdx.x * 256 + threadIdx.x;
    if (i < n) x[i] = fmaxf(x[i], 0.f);
}

// ---------------- fused post-processing: one block per graph ----------------
__device__ __forceinline__ float sigmoidf(float x) { return 1.f / (1.f + expf(-x)); }

__global__ __launch_bounds__(256) void post_kernel(
    const float* __restrict__ d1g, const float* __restrict__ d2g,
    const float* __restrict__ attW, const float* __restrict__ tW,
    const float* __restrict__ tblk, const float* __restrict__ tbias,
    const float* __restrict__ sW1, const float* __restrict__ sb1,
    const float* __restrict__ sW2, const float* __restrict__ sb2,
    float* __restrict__ outp) {
    __shared__ float s1[NPG * (F3 + 1)];
    __shared__ float s2[NPG * (F3 + 1)];
    __shared__ float red[16];
    __shared__ float mean1[F3], mean2[F3], ctx1[F3], ctx2[F3];
    __shared__ float a1[NPG], a2[NPG];
    __shared__ float e1[F3], e2[F3];
    __shared__ int bins[BINS];
    __shared__ float feat[TN + BINS];
    __shared__ float hvec[16];
    __shared__ float lohi[2];

    int g = blockIdx.x;
    int tid = threadIdx.x;

    for (int i = tid; i < NPG * F3; i += 256) {
        int n = i >> 5, c = i & 31;
        s1[n * 33 + c] = d1g[g * NPG * F3 + i];
        s2[n * 33 + c] = d2g[g * NPG * F3 + i];
    }
    if (tid < BINS) bins[tid] = 0;
    __syncthreads();

    // pass 1: raw-score min/max (sigmoid is monotone)
    float lmin = 1e30f, lmax = -1e30f;
    for (int i = tid; i < NPG * NPG; i += 256) {
        int n = i >> 7, m = i & 127;
        float acc = 0.f;
#pragma unroll
        for (int k = 0; k < F3; ++k) acc += s1[n * 33 + k] * s2[m * 33 + k];
        lmin = fminf(lmin, acc);
        lmax = fmaxf(lmax, acc);
    }
    for (int off = 32; off; off >>= 1) {
        lmin = fminf(lmin, __shfl_down(lmin, off));
        lmax = fmaxf(lmax, __shfl_down(lmax, off));
    }
    int wid = tid >> 6, lane = tid & 63;
    if (lane == 0) { red[wid] = lmin; red[8 + wid] = lmax; }
    __syncthreads();
    if (tid == 0) {
        float mn = red[0], mx = red[8];
        for (int w = 1; w < 4; ++w) { mn = fminf(mn, red[w]); mx = fmaxf(mx, red[8 + w]); }
        lohi[0] = sigmoidf(mn);
        lohi[1] = sigmoidf(mx);
    }
    __syncthreads();
    float lo = lohi[0];
    float denom = fmaxf(lohi[1] - lo, 1e-12f);

    // pass 2: histogram (recompute scores; cheaper than 64KB LDS)
    for (int i = tid; i < NPG * NPG; i += 256) {
        int n = i >> 7, m = i & 127;
        float acc = 0.f;
#pragma unroll
        for (int k = 0; k < F3; ++k) acc += s1[n * 33 + k] * s2[m * 33 + k];
        float v = sigmoidf(acc);
        int b = (int)floorf((v - lo) / denom * (float)BINS);
        b = min(max(b, 0), BINS - 1);
        atomicAdd(&bins[b], 1);
    }

    // attention pooling (mean over nodes commutes with @attW)
    if (tid < F3) {
        float s = 0.f;
        for (int n = 0; n < NPG; ++n) s += s1[n * 33 + tid];
        mean1[tid] = s * (1.f / NPG);
    } else if (tid < 2 * F3) {
        int c = tid - F3;
        float s = 0.f;
        for (int n = 0; n < NPG; ++n) s += s2[n * 33 + c];
        mean2[c] = s * (1.f / NPG);
    }
    __syncthreads();
    if (tid < F3) {
        float acc = 0.f;
        for (int k = 0; k < F3; ++k) acc += mean1[k] * attW[k * F3 + tid];
        ctx1[tid] = tanhf(acc);
    } else if (tid < 2 * F3) {
        int c = tid - F3;
        float acc = 0.f;
        for (int k = 0; k < F3; ++k) acc += mean2[k] * attW[k * F3 + c];
        ctx2[c] = tanhf(acc);
    }
    __syncthreads();
    if (tid < NPG) {
        float acc = 0.f;
        for (int k = 0; k < F3; ++k) acc += s1[tid * 33 + k] * ctx1[k];
        a1[tid] = sigmoidf(acc);
    } else {
        int n = tid - NPG;
        float acc = 0.f;
        for (int k = 0; k < F3; ++k) acc += s2[n * 33 + k] * ctx2[k];
        a2[n] = sigmoidf(acc);
    }
    __syncthreads();
    if (tid < F3) {
        float acc = 0.f;
        for (int n = 0; n < NPG; ++n) acc += a1[n] * s1[n * 33 + tid];
        e1[tid] = acc;
    } else if (tid < 2 * F3) {
        int c = tid - F3;
        float acc = 0.f;
        for (int n = 0; n < NPG; ++n) acc += a2[n] * s2[n * 33 + c];
        e2[c] = acc;
    }
    __syncthreads();

    // tensor network + histogram feature
    if (tid < TN) {
        float acc = 0.f;
        for (int i = 0; i < F3; ++i) {
            float ei = e1[i];
            for (int j = 0; j < F3; ++j)
                acc += ei * e2[j] * tW[(i * F3 + j) * TN + tid];
        }
        float bs = 0.f;
        for (int i = 0; i < F3; ++i) bs += e1[i] * tblk[tid * 2 * F3 + i];
        for (int j = 0; j < F3; ++j) bs += e2[j] * tblk[tid * 2 * F3 + F3 + j];
        feat[tid] = fmaxf(acc + bs + tbias[tid], 0.f);
    } else if (tid < TN + BINS) {
        feat[tid] = (float)bins[tid - TN] * (1.f / (NPG * NPG));
    }
    __syncthreads();
    if (tid < 16) {
        float acc = sb1[tid];
        for (int i = 0; i < TN + BINS; ++i) acc += feat[i] * sW1[i * 16 + tid];
        hvec[tid] = fmaxf(acc, 0.f);
    }
    __syncthreads();
    if (tid == 0) {
        float acc = sb2[0];
        for (int j = 0; j < 16; ++j) acc += hvec[j] * sW2[j];
        outp[g] = sigmoidf(acc);
    }
}

// ---------------- launch ----------------
extern "C" void kernel_launch(void* const* d_in, const int* in_sizes, int n_in,
                              void* d_out, int out_size, void* d_ws, size_t ws_size,
                              hipStream_t stream) {
    const float* x1   = (const float*)d_in[0];
    const int*   ei1  = (const int*)d_in[1];
    const float* x2   = (const float*)d_in[3];
    const int*   ei2  = (const int*)d_in[4];
    const float* W1   = (const float*)d_in[6];
    const float* b1   = (const float*)d_in[7];
    const float* W2   = (const float*)d_in[8];
    const float* b2   = (const float*)d_in[9];
    const float* W3   = (const float*)d_in[10];
    const float* b3   = (const float*)d_in[11];
    const float* attW = (const float*)d_in[12];
    const float* tW   = (const float*)d_in[13];
    const float* tblk = (const float*)d_in[14];
    const float* tbias= (const float*)d_in[15];
    const float* sW1  = (const float*)d_in[16];
    const float* sb1  = (const float*)d_in[17];
    const float* sW2  = (const float*)d_in[18];
    const float* sb2  = (const float*)d_in[19];
    float* out = (float*)d_out;

    float* bufA = (float*)d_ws;                    // N*128
    float* bufB = bufA + (size_t)N_NODES * 128;    // N*128
    float* dt1  = bufB + (size_t)N_NODES * 128;    // N*32
    float* dt2  = dt1 + (size_t)N_NODES * F3;      // N*32
    float* dinv = dt2 + (size_t)N_NODES * F3;      // N
    int*   deg  = (int*)(dinv + N_NODES);          // N

    for (int side = 0; side < 2; ++side) {
        const float* x   = side ? x2 : x1;
        const int*   src = side ? ei2 : ei1;
        const int*   dst = src + N_EDGES;
        float*       dt  = side ? dt2 : dt1;

        deg_init<<<N_NODES / 256, 256, 0, stream>>>(deg);
        deg_accum<<<N_EDGES / 256, 256, 0, stream>>>(dst, deg);
        deg_fin<<<N_NODES / 256, 256, 0, stream>>>(deg, dinv);

        // layer 1: 64 -> 128, relu
        mm_kernel<F_IN, F1><<<N_NODES / 2, 256, 0, stream>>>(x, W1, bufA);
        agg_init<F1><<<N_NODES * F1 / 256, 256, 0, stream>>>(bufA, dinv, b1, bufB);
        agg_edge<F1><<<N_EDGES * F1 / 256, 256, 0, stream>>>(src, dst, bufA, dinv, bufB);
        relu_k<<<N_NODES * F1 / 256, 256, 0, stream>>>(bufB, N_NODES * F1);

        // layer 2: 128 -> 64, relu
        mm_kernel<F1, F2><<<N_NODES / 4, 256, 0, stream>>>(bufB, W2, bufA);
        agg_init<F2><<<N_NODES * F2 / 256, 256, 0, stream>>>(bufA, dinv, b2, bufB);
        agg_edge<F2><<<N_EDGES * F2 / 256, 256, 0, stream>>>(src, dst, bufA, dinv, bufB);
        relu_k<<<N_NODES * F2 / 256, 256, 0, stream>>>(bufB, N_NODES * F2);

        // layer 3: 64 -> 32, no relu
        mm_kernel<F2, F3><<<N_NODES / 8, 256, 0, stream>>>(bufB, W3, bufA);
        agg_init<F3><<<N_NODES * F3 / 256, 256, 0, stream>>>(bufA, dinv, b3, dt);
        agg_edge<F3><<<N_EDGES * F3 / 256, 256, 0, stream>>>(src, dst, bufA, dinv, dt);
    }

    post_kernel<<<NGRAPH, 256, 0, stream>>>(dt1, dt2, attW, tW, tblk, tbias,
                                            sW1, sb1, sW2, sb2, out);
}

// Round 3
// 547.277 us; speedup vs baseline: 2.0037x; 2.0037x over previous
//
#include <hip/hip_runtime.h>
#include <hip/hip_bf16.h>

// Problem constants (fixed by the reference harness)
#define N_NODES 32768
#define N_EDGES 524288
#define NGRAPH  256
#define NPG     128
#define F_IN    64
#define F1      128
#define F2      64
#define F3      32
#define TN      16
#define BINS    16

// ---------------- CSR build ----------------
__global__ void zero_int(int* __restrict__ p, int n) {
    int i = blockIdx.x * 256 + threadIdx.x;
    if (i < n) p[i] = 0;
}
__global__ void csr_count(const int* __restrict__ dst, int* __restrict__ cnt) {
    int e = blockIdx.x * 256 + threadIdx.x;
    if (e < N_EDGES) atomicAdd(&cnt[dst[e]], 1);
}
__global__ void make_dinv(const int* __restrict__ cnt, float* __restrict__ dinv) {
    int i = blockIdx.x * 256 + threadIdx.x;
    if (i < N_NODES) dinv[i] = rsqrtf((float)cnt[i] + 1.0f);  // +1 self loop
}
// single-block scan over 32768 counts -> rowptr (exclusive), cursor copy
__global__ __launch_bounds__(1024) void scan_k(const int* __restrict__ cnt,
                                               int* __restrict__ rowptr,
                                               int* __restrict__ cursor) {
    __shared__ int sums[1024];
    int t = threadIdx.x;
    int base = t * 32;
    int local[32];
    int s = 0;
#pragma unroll
    for (int i = 0; i < 32; ++i) { local[i] = s; s += cnt[base + i]; }
    sums[t] = s;
    __syncthreads();
    for (int stp = 1; stp < 1024; stp <<= 1) {
        int v = (t >= stp) ? sums[t - stp] : 0;
        __syncthreads();
        sums[t] += v;
        __syncthreads();
    }
    int off = sums[t] - s;  // exclusive
#pragma unroll
    for (int i = 0; i < 32; ++i) {
        int r = off + local[i];
        rowptr[base + i] = r;
        cursor[base + i] = r;
    }
    if (t == 1023) rowptr[N_NODES] = off + s;
}
__global__ void csr_scatter(const int* __restrict__ src, const int* __restrict__ dst,
                            const float* __restrict__ dinv, int* __restrict__ cursor,
                            int* __restrict__ esrc, float* __restrict__ enorm) {
    int e = blockIdx.x * 256 + threadIdx.x;
    if (e < N_EDGES) {
        int s = src[e], d = dst[e];
        int p = atomicAdd(&cursor[d], 1);
        esrc[p] = s;
        enorm[p] = dinv[s] * dinv[d];
    }
}

// ---------------- fused gather-aggregate (replaces atomics) ----------------
// out[n,c] = sum_j norm_j * h[src_j, c] + dinv[n]^2 * h[n,c] (+ bias)(+ relu)
template<int F, bool BIAS, bool RELU>
__global__ __launch_bounds__(256) void agg_gather(const float* __restrict__ h,
                                                  const int* __restrict__ rowptr,
                                                  const int* __restrict__ esrc,
                                                  const float* __restrict__ enorm,
                                                  const float* __restrict__ dinv,
                                                  const float* __restrict__ bias,
                                                  float* __restrict__ out) {
    constexpr int GP = 256 / F;
    int n = blockIdx.x * GP + threadIdx.x / F;
    int c = threadIdx.x % F;
    int r0 = rowptr[n], r1 = rowptr[n + 1];
    float di = dinv[n];
    float acc = di * di * h[(size_t)n * F + c];
    for (int j = r0; j < r1; ++j) {
        int s = esrc[j];
        float w = enorm[j];
        acc += w * h[(size_t)s * F + c];
    }
    if (BIAS) acc += bias[c];
    if (RELU) acc = fmaxf(acc, 0.f);
    out[(size_t)n * F + c] = acc;
}

// ---------------- dense matmul: out[N,FOUT] = x[N,FIN] @ W[FIN,FOUT] (+b)(relu) ----------------
template<int FIN, int FOUT, bool BIAS, bool RELU>
__global__ __launch_bounds__(256) void mm_kernel(const float* __restrict__ x,
                                                 const float* __restrict__ W,
                                                 const float* __restrict__ b,
                                                 float* __restrict__ out) {
    constexpr int ROWS = 256 / FOUT;
    __shared__ float xs[ROWS * FIN];
    int n0 = blockIdx.x * ROWS;
    for (int i = threadIdx.x; i < ROWS * FIN; i += 256) xs[i] = x[(size_t)n0 * FIN + i];
    __syncthreads();
    int r = threadIdx.x / FOUT;
    int c = threadIdx.x % FOUT;
    float acc = 0.f;
#pragma unroll
    for (int k = 0; k < FIN; ++k) acc += xs[r * FIN + k] * W[k * FOUT + c];
    if (BIAS) acc += b[c];
    if (RELU) acc = fmaxf(acc, 0.f);
    out[(size_t)(n0 + r) * FOUT + c] = acc;
}

// ---------------- fused post-processing: one block per graph ----------------
__device__ __forceinline__ float sigmoidf(float x) { return 1.f / (1.f + expf(-x)); }

__global__ __launch_bounds__(256) void post_kernel(
    const float* __restrict__ d1g, const float* __restrict__ d2g,
    const float* __restrict__ attW, const float* __restrict__ tW,
    const float* __restrict__ tblk, const float* __restrict__ tbias,
    const float* __restrict__ sW1, const float* __restrict__ sb1,
    const float* __restrict__ sW2, const float* __restrict__ sb2,
    float* __restrict__ outp) {
    __shared__ float s1[NPG * (F3 + 1)];
    __shared__ float s2[NPG * (F3 + 1)];
    __shared__ float red[16];
    __shared__ float mean1[F3], mean2[F3], ctx1[F3], ctx2[F3];
    __shared__ float a1[NPG], a2[NPG];
    __shared__ float e1[F3], e2[F3];
    __shared__ int bins[BINS];
    __shared__ float feat[TN + BINS];
    __shared__ float hvec[16];
    __shared__ float lohi[2];

    int g = blockIdx.x;
    int tid = threadIdx.x;

    for (int i = tid; i < NPG * F3; i += 256) {
        int n = i >> 5, c = i & 31;
        s1[n * 33 + c] = d1g[g * NPG * F3 + i];
        s2[n * 33 + c] = d2g[g * NPG * F3 + i];
    }
    if (tid < BINS) bins[tid] = 0;
    __syncthreads();

    // pass 1: raw-score min/max (sigmoid is monotone)
    float lmin = 1e30f, lmax = -1e30f;
    for (int i = tid; i < NPG * NPG; i += 256) {
        int n = i >> 7, m = i & 127;
        float acc = 0.f;
#pragma unroll
        for (int k = 0; k < F3; ++k) acc += s1[n * 33 + k] * s2[m * 33 + k];
        lmin = fminf(lmin, acc);
        lmax = fmaxf(lmax, acc);
    }
    for (int off = 32; off; off >>= 1) {
        lmin = fminf(lmin, __shfl_down(lmin, off));
        lmax = fmaxf(lmax, __shfl_down(lmax, off));
    }
    int wid = tid >> 6, lane = tid & 63;
    if (lane == 0) { red[wid] = lmin; red[8 + wid] = lmax; }
    __syncthreads();
    if (tid == 0) {
        float mn = red[0], mx = red[8];
        for (int w = 1; w < 4; ++w) { mn = fminf(mn, red[w]); mx = fmaxf(mx, red[8 + w]); }
        lohi[0] = sigmoidf(mn);
        lohi[1] = sigmoidf(mx);
    }
    __syncthreads();
    float lo = lohi[0];
    float denom = fmaxf(lohi[1] - lo, 1e-12f);

    // pass 2: histogram (recompute scores; cheaper than 64KB LDS)
    for (int i = tid; i < NPG * NPG; i += 256) {
        int n = i >> 7, m = i & 127;
        float acc = 0.f;
#pragma unroll
        for (int k = 0; k < F3; ++k) acc += s1[n * 33 + k] * s2[m * 33 + k];
        float v = sigmoidf(acc);
        int b = (int)floorf((v - lo) / denom * (float)BINS);
        b = min(max(b, 0), BINS - 1);
        atomicAdd(&bins[b], 1);
    }

    // attention pooling (mean over nodes commutes with @attW)
    if (tid < F3) {
        float s = 0.f;
        for (int n = 0; n < NPG; ++n) s += s1[n * 33 + tid];
        mean1[tid] = s * (1.f / NPG);
    } else if (tid < 2 * F3) {
        int c = tid - F3;
        float s = 0.f;
        for (int n = 0; n < NPG; ++n) s += s2[n * 33 + c];
        mean2[c] = s * (1.f / NPG);
    }
    __syncthreads();
    if (tid < F3) {
        float acc = 0.f;
        for (int k = 0; k < F3; ++k) acc += mean1[k] * attW[k * F3 + tid];
        ctx1[tid] = tanhf(acc);
    } else if (tid < 2 * F3) {
        int c = tid - F3;
        float acc = 0.f;
        for (int k = 0; k < F3; ++k) acc += mean2[k] * attW[k * F3 + c];
        ctx2[c] = tanhf(acc);
    }
    __syncthreads();
    if (tid < NPG) {
        float acc = 0.f;
        for (int k = 0; k < F3; ++k) acc += s1[tid * 33 + k] * ctx1[k];
        a1[tid] = sigmoidf(acc);
    } else {
        int n = tid - NPG;
        float acc = 0.f;
        for (int k = 0; k < F3; ++k) acc += s2[n * 33 + k] * ctx2[k];
        a2[n] = sigmoidf(acc);
    }
    __syncthreads();
    if (tid < F3) {
        float acc = 0.f;
        for (int n = 0; n < NPG; ++n) acc += a1[n] * s1[n * 33 + tid];
        e1[tid] = acc;
    } else if (tid < 2 * F3) {
        int c = tid - F3;
        float acc = 0.f;
        for (int n = 0; n < NPG; ++n) acc += a2[n] * s2[n * 33 + c];
        e2[c] = acc;
    }
    __syncthreads();

    // tensor network + histogram feature
    if (tid < TN) {
        float acc = 0.f;
        for (int i = 0; i < F3; ++i) {
            float ei = e1[i];
            for (int j = 0; j < F3; ++j)
                acc += ei * e2[j] * tW[(i * F3 + j) * TN + tid];
        }
        float bs = 0.f;
        for (int i = 0; i < F3; ++i) bs += e1[i] * tblk[tid * 2 * F3 + i];
        for (int j = 0; j < F3; ++j) bs += e2[j] * tblk[tid * 2 * F3 + F3 + j];
        feat[tid] = fmaxf(acc + bs + tbias[tid], 0.f);
    } else if (tid < TN + BINS) {
        feat[tid] = (float)bins[tid - TN] * (1.f / (NPG * NPG));
    }
    __syncthreads();
    if (tid < 16) {
        float acc = sb1[tid];
        for (int i = 0; i < TN + BINS; ++i) acc += feat[i] * sW1[i * 16 + tid];
        hvec[tid] = fmaxf(acc, 0.f);
    }
    __syncthreads();
    if (tid == 0) {
        float acc = sb2[0];
        for (int j = 0; j < 16; ++j) acc += hvec[j] * sW2[j];
        outp[g] = sigmoidf(acc);
    }
}

// ---------------- launch ----------------
extern "C" void kernel_launch(void* const* d_in, const int* in_sizes, int n_in,
                              void* d_out, int out_size, void* d_ws, size_t ws_size,
                              hipStream_t stream) {
    const float* x1   = (const float*)d_in[0];
    const int*   ei1  = (const int*)d_in[1];
    const float* x2   = (const float*)d_in[3];
    const int*   ei2  = (const int*)d_in[4];
    const float* W1   = (const float*)d_in[6];
    const float* b1   = (const float*)d_in[7];
    const float* W2   = (const float*)d_in[8];
    const float* b2   = (const float*)d_in[9];
    const float* W3   = (const float*)d_in[10];
    const float* b3   = (const float*)d_in[11];
    const float* attW = (const float*)d_in[12];
    const float* tW   = (const float*)d_in[13];
    const float* tblk = (const float*)d_in[14];
    const float* tbias= (const float*)d_in[15];
    const float* sW1  = (const float*)d_in[16];
    const float* sb1  = (const float*)d_in[17];
    const float* sW2  = (const float*)d_in[18];
    const float* sb2  = (const float*)d_in[19];
    float* out = (float*)d_out;

    float* bufA = (float*)d_ws;                    // N*128 f
    float* bufB = bufA + (size_t)N_NODES * 128;    // N*128 f
    float* dt1  = bufB + (size_t)N_NODES * 128;    // N*32 f
    float* dt2  = dt1 + (size_t)N_NODES * F3;      // N*32 f
    float* dinv = dt2 + (size_t)N_NODES * F3;      // N f
    int*   cnt  = (int*)(dinv + N_NODES);          // N i
    int*   rowp = cnt + N_NODES;                   // N+1 i
    int*   curs = rowp + N_NODES + 1;              // N i
    int*   esrc = curs + N_NODES;                  // E i
    float* enorm= (float*)(esrc + N_EDGES);        // E f

    for (int side = 0; side < 2; ++side) {
        const float* x   = side ? x2 : x1;
        const int*   src = side ? ei2 : ei1;
        const int*   dst = src + N_EDGES;
        float*       dt  = side ? dt2 : dt1;

        // CSR build
        zero_int<<<N_NODES / 256, 256, 0, stream>>>(cnt, N_NODES);
        csr_count<<<N_EDGES / 256, 256, 0, stream>>>(dst, cnt);
        make_dinv<<<N_NODES / 256, 256, 0, stream>>>(cnt, dinv);
        scan_k<<<1, 1024, 0, stream>>>(cnt, rowp, curs);
        csr_scatter<<<N_EDGES / 256, 256, 0, stream>>>(src, dst, dinv, curs, esrc, enorm);

        // layer 1: (A~ x) @ W1 + b1, relu   [agg at F=64 instead of 128]
        agg_gather<F_IN, false, false><<<N_NODES * F_IN / 256, 256, 0, stream>>>(
            x, rowp, esrc, enorm, dinv, nullptr, bufA);
        mm_kernel<F_IN, F1, true, true><<<N_NODES / 2, 256, 0, stream>>>(bufA, W1, b1, bufB);

        // layer 2: A~ (h1 @ W2) + b2, relu
        mm_kernel<F1, F2, false, false><<<N_NODES / 4, 256, 0, stream>>>(bufB, W2, nullptr, bufA);
        agg_gather<F2, true, true><<<N_NODES * F2 / 256, 256, 0, stream>>>(
            bufA, rowp, esrc, enorm, dinv, b2, bufB);

        // layer 3: A~ (h2 @ W3) + b3
        mm_kernel<F2, F3, false, false><<<N_NODES / 8, 256, 0, stream>>>(bufB, W3, nullptr, bufA);
        agg_gather<F3, true, false><<<N_NODES * F3 / 256, 256, 0, stream>>>(
            bufA, rowp, esrc, enorm, dinv, b3, dt);
    }

    post_kernel<<<NGRAPH, 256, 0, stream>>>(dt1, dt2, attW, tW, tblk, tbias,
                                            sW1, sb1, sW2, sb2, out);
}

// Round 5
// 397.634 us; speedup vs baseline: 2.7578x; 1.3763x over previous
//
#include <hip/hip_runtime.h>
#include <hip/hip_bf16.h>

// Problem constants (fixed by the reference harness)
#define N_NODES 32768
#define N_EDGES 524288
#define N2 (2 * N_NODES)     // both sides merged into one graph
#define E2 (2 * N_EDGES)
#define NGRAPH  256
#define NPG     128
#define F_IN    64
#define F1      128
#define F2      64
#define F3      32
#define TN      16
#define BINS    16

// ---------------- CSR build (both sides in one pass) ----------------
__global__ void zero_int(int* __restrict__ p, int n) {
    int i = blockIdx.x * 256 + threadIdx.x;
    if (i < n) p[i] = 0;
}
__global__ void csr_count2(const int* __restrict__ d1, const int* __restrict__ d2,
                           int* __restrict__ cnt) {
    int e = blockIdx.x * 256 + threadIdx.x;           // 0..2E-1, exact grid
    int d = (e < N_EDGES) ? d1[e] : N_NODES + d2[e - N_EDGES];
    atomicAdd(&cnt[d], 1);
}
// single-block scan over 2N counts -> rowptr (exclusive), cursor copy, dinv
__global__ __launch_bounds__(1024) void scan_k(const int* __restrict__ cnt,
                                               int* __restrict__ rowptr,
                                               int* __restrict__ cursor,
                                               float* __restrict__ dinv) {
    __shared__ int sums[1024];
    int t = threadIdx.x;
    int base = t * 64;
    int local[64];
    int s = 0;
#pragma unroll
    for (int i = 0; i < 64; i += 4) {
        int4 c4 = *(const int4*)&cnt[base + i];
        local[i + 0] = s; s += c4.x;
        local[i + 1] = s; s += c4.y;
        local[i + 2] = s; s += c4.z;
        local[i + 3] = s; s += c4.w;
        dinv[base + i + 0] = rsqrtf((float)c4.x + 1.0f);
        dinv[base + i + 1] = rsqrtf((float)c4.y + 1.0f);
        dinv[base + i + 2] = rsqrtf((float)c4.z + 1.0f);
        dinv[base + i + 3] = rsqrtf((float)c4.w + 1.0f);
    }
    sums[t] = s;
    __syncthreads();
    for (int stp = 1; stp < 1024; stp <<= 1) {
        int v = (t >= stp) ? sums[t - stp] : 0;
        __syncthreads();
        sums[t] += v;
        __syncthreads();
    }
    int off = sums[t] - s;  // exclusive
#pragma unroll
    for (int i = 0; i < 64; i += 4) {
        int4 r4 = make_int4(off + local[i], off + local[i + 1],
                            off + local[i + 2], off + local[i + 3]);
        *(int4*)&rowptr[base + i] = r4;
        *(int4*)&cursor[base + i] = r4;
    }
    if (t == 1023) rowptr[N2] = off + s;
}
__global__ void csr_scatter2(const int* __restrict__ s1, const int* __restrict__ d1,
                             const int* __restrict__ s2, const int* __restrict__ d2,
                             int* __restrict__ cursor, int* __restrict__ esrc) {
    int e = blockIdx.x * 256 + threadIdx.x;
    int s, d;
    if (e < N_EDGES) { s = s1[e]; d = d1[e]; }
    else             { s = N_NODES + s2[e - N_EDGES]; d = N_NODES + d2[e - N_EDGES]; }
    int p = atomicAdd(&cursor[d], 1);
    esrc[p] = s;
}

// ---------------- gather-aggregate ----------------
// out[n,c] = dinv[n] * sum_j dinv[s_j] * h[s_j, c] + dinv[n]^2 * h[n,c] (+bias)(+relu)
__global__ __launch_bounds__(256) void agg_gather_x(const float* __restrict__ x1,
                                                    const float* __restrict__ x2,
                                                    const int* __restrict__ rowptr,
                                                    const int* __restrict__ esrc,
                                                    const float* __restrict__ dinv,
                                                    float* __restrict__ out) {
    int n = blockIdx.x * 4 + (threadIdx.x >> 6);
    int c = threadIdx.x & 63;
    int r0 = rowptr[n], r1 = rowptr[n + 1];
    float di = dinv[n];
    const float* xn = (n < N_NODES) ? x1 + (size_t)n * F_IN
                                    : x2 + (size_t)(n - N_NODES) * F_IN;
    float acc = 0.f;
    for (int j = r0; j < r1; ++j) {
        int s = esrc[j];
        const float* xs = (s < N_NODES) ? x1 + (size_t)s * F_IN
                                        : x2 + (size_t)(s - N_NODES) * F_IN;
        acc += dinv[s] * xs[c];
    }
    out[(size_t)n * F_IN + c] = di * (acc + di * xn[c]);
}

template<int F, bool BIAS, bool RELU>
__global__ __launch_bounds__(256) void agg_gather(const float* __restrict__ h,
                                                  const int* __restrict__ rowptr,
                                                  const int* __restrict__ esrc,
                                                  const float* __restrict__ dinv,
                                                  const float* __restrict__ bias,
                                                  float* __restrict__ out) {
    constexpr int GP = 256 / F;
    int n = blockIdx.x * GP + threadIdx.x / F;
    int c = threadIdx.x % F;
    int r0 = rowptr[n], r1 = rowptr[n + 1];
    float di = dinv[n];
    float acc = 0.f;
    for (int j = r0; j < r1; ++j) {
        int s = esrc[j];
        acc += dinv[s] * h[(size_t)s * F + c];
    }
    acc = di * (acc + di * h[(size_t)n * F + c]);
    if (BIAS) acc += bias[c];
    if (RELU) acc = fmaxf(acc, 0.f);
    out[(size_t)n * F + c] = acc;
}

// ---------------- tiled matmul: out[N2,FOUT] = x[N2,FIN] @ W (+b)(relu) ----------------
// 256 threads; each computes RPT rows x 4 cols. W and transposed-x staged in LDS.
template<int FIN, int FOUT, int BM, bool BIAS, bool RELU>
__global__ __launch_bounds__(256) void mm_tiled(const float* __restrict__ x,
                                                const float* __restrict__ W,
                                                const float* __restrict__ b,
                                                float* __restrict__ out) {
    constexpr int BMp = BM + 4;               // 16B-aligned padded stride
    constexpr int CX = FOUT / 4;              // thread-cols
    constexpr int RPT = BM / (256 / CX);      // rows per thread
    __shared__ float Wl[FIN * FOUT];
    __shared__ float xT[FIN * BMp];
    int tid = threadIdx.x;
    size_t n0 = (size_t)blockIdx.x * BM;

    for (int i = tid * 4; i < FIN * FOUT; i += 1024)
        *(float4*)&Wl[i] = *(const float4*)&W[i];
    for (int i = tid * 4; i < BM * FIN; i += 1024) {
        float4 v = *(const float4*)&x[n0 * FIN + i];
        int r = i / FIN, k = i % FIN;
        xT[(k + 0) * BMp + r] = v.x;
        xT[(k + 1) * BMp + r] = v.y;
        xT[(k + 2) * BMp + r] = v.z;
        xT[(k + 3) * BMp + r] = v.w;
    }
    __syncthreads();

    int cx = tid % CX, ry = tid / CX;
    int c0 = cx * 4, r0 = ry * RPT;
    float acc[RPT][4] = {};
#pragma unroll 8
    for (int k = 0; k < FIN; ++k) {
        float4 w4 = *(float4*)&Wl[k * FOUT + c0];
        float xr[RPT];
#pragma unroll
        for (int r = 0; r < RPT; ++r) xr[r] = xT[k * BMp + r0 + r];
#pragma unroll
        for (int r = 0; r < RPT; ++r) {
            acc[r][0] += xr[r] * w4.x;
            acc[r][1] += xr[r] * w4.y;
            acc[r][2] += xr[r] * w4.z;
            acc[r][3] += xr[r] * w4.w;
        }
    }
#pragma unroll
    for (int r = 0; r < RPT; ++r) {
        float4 o;
        o.x = acc[r][0]; o.y = acc[r][1]; o.z = acc[r][2]; o.w = acc[r][3];
        if (BIAS) { o.x += b[c0]; o.y += b[c0 + 1]; o.z += b[c0 + 2]; o.w += b[c0 + 3]; }
        if (RELU) { o.x = fmaxf(o.x, 0.f); o.y = fmaxf(o.y, 0.f);
                    o.z = fmaxf(o.z, 0.f); o.w = fmaxf(o.w, 0.f); }
        *(float4*)&out[(n0 + r0 + r) * FOUT + c0] = o;
    }
}

// ---------------- fused post-processing: one 512-thread block per graph ----------------
__device__ __forceinline__ float sigmoidf(float x) { return 1.f / (1.f + expf(-x)); }

#define ST 132   // padded row stride for transposed score operands

__global__ __launch_bounds__(512) void post_kernel(
    const float* __restrict__ dt,            // [N2, F3]; side2 at +N_NODES rows
    const float* __restrict__ attW, const float* __restrict__ tW,
    const float* __restrict__ tblk, const float* __restrict__ tbias,
    const float* __restrict__ sW1, const float* __restrict__ sb1,
    const float* __restrict__ sW2, const float* __restrict__ sb2,
    float* __restrict__ outp) {
    __shared__ float s1T[F3 * ST];           // [k][n] transposed, 16.9KB
    __shared__ float s2T[F3 * ST];
    __shared__ unsigned short lhist[512 * 17];  // per-thread private bins, 17.4KB
    __shared__ float red[16];
    __shared__ float lohi[2];
    __shared__ int   bins2[16 * 16];
    __shared__ float pmean[8 * 64];
    __shared__ float meanv[64], ctxv[64], av[256], ev[64];
    __shared__ float ptens[32 * 16];
    __shared__ float feat[TN + BINS];
    __shared__ float hv[16];

    int g = blockIdx.x;
    int tid = threadIdx.x;
    const float* d1g = dt + (size_t)g * NPG * F3;
    const float* d2g = dt + (size_t)(N_NODES + g * NPG) * F3;

    // stage transposed: sT[c*ST + n]
    for (int i = tid; i < NPG * F3; i += 512) {
        int n = i >> 5, c = i & 31;
        s1T[c * ST + n] = d1g[i];
        s2T[c * ST + n] = d2g[i];
    }
    for (int i = tid; i < 512 * 17 / 2; i += 512) ((unsigned int*)lhist)[i] = 0u;
    __syncthreads();

    // ---- scores once into registers: 4 n-rows x 8 m-cols per thread ----
    int ny = tid >> 4, mx = tid & 15;
    int n0 = ny * 4, m0 = mx * 8;
    float sc[4][8];
#pragma unroll
    for (int r = 0; r < 4; ++r)
#pragma unroll
        for (int m = 0; m < 8; ++m) sc[r][m] = 0.f;
#pragma unroll 4
    for (int k = 0; k < F3; ++k) {
        float4 a4 = *(float4*)&s1T[k * ST + n0];
        float4 b4 = *(float4*)&s2T[k * ST + m0];
        float4 c4 = *(float4*)&s2T[k * ST + m0 + 4];
        float av_[4] = {a4.x, a4.y, a4.z, a4.w};
        float bv[8] = {b4.x, b4.y, b4.z, b4.w, c4.x, c4.y, c4.z, c4.w};
#pragma unroll
        for (int r = 0; r < 4; ++r)
#pragma unroll
            for (int m = 0; m < 8; ++m) sc[r][m] += av_[r] * bv[m];
    }
    // min/max (raw space; sigmoid is monotone)
    float lmin = sc[0][0], lmax = sc[0][0];
#pragma unroll
    for (int r = 0; r < 4; ++r)
#pragma unroll
        for (int m = 0; m < 8; ++m) {
            lmin = fminf(lmin, sc[r][m]);
            lmax = fmaxf(lmax, sc[r][m]);
        }
    for (int off = 32; off; off >>= 1) {
        lmin = fminf(lmin, __shfl_down(lmin, off));
        lmax = fmaxf(lmax, __shfl_down(lmax, off));
    }
    int wid = tid >> 6;
    if ((tid & 63) == 0) { red[wid] = lmin; red[8 + wid] = lmax; }
    __syncthreads();
    if (tid == 0) {
        float mn = red[0], mx_ = red[8];
        for (int w = 1; w < 8; ++w) { mn = fminf(mn, red[w]); mx_ = fmaxf(mx_, red[8 + w]); }
        lohi[0] = sigmoidf(mn);
        lohi[1] = sigmoidf(mx_);
    }
    __syncthreads();
    float lo = lohi[0];
    float denom = fmaxf(lohi[1] - lo, 1e-12f);

    // ---- histogram from registers into private counters ----
    {
        unsigned short* lh = &lhist[tid * 17];
#pragma unroll
        for (int r = 0; r < 4; ++r)
#pragma unroll
            for (int m = 0; m < 8; ++m) {
                float v = sigmoidf(sc[r][m]);
                int bidx = (int)floorf((v - lo) / denom * (float)BINS);
                bidx = min(max(bidx, 0), BINS - 1);
                lh[bidx]++;
            }
    }
    __syncthreads();
    // reduce 512x16 -> 16
    if (tid < 256) {
        int b = tid & 15, chunk = tid >> 4;  // 16 chunks x 32 rows
        int s = 0;
        for (int i = 0; i < 32; ++i) s += lhist[(chunk * 32 + i) * 17 + b];
        bins2[chunk * 16 + b] = s;
    }
    __syncthreads();

    // ---- attention pooling, parallel ----
    // column means: col 0..63 (side = col>=32), 8 chunks of 16 nodes
    {
        int col = tid & 63, chunk = tid >> 6;
        const float* sT = (col < 32) ? &s1T[col * ST] : &s2T[(col - 32) * ST];
        float s = 0.f;
        int nb = chunk * 16;
        for (int n = 0; n < 16; ++n) s += sT[nb + n];
        pmean[chunk * 64 + col] = s;
    }
    __syncthreads();
    if (tid < 64) {
        float s = 0.f;
        for (int c = 0; c < 8; ++c) s += pmean[c * 64 + tid];
        meanv[tid] = s * (1.f / NPG);
    }
    __syncthreads();
    if (tid < 64) {
        int c = tid & 31;
        const float* mv = &meanv[(tid >> 5) * 32];
        float acc = 0.f;
        for (int k = 0; k < F3; ++k) acc += mv[k] * attW[k * F3 + c];
        ctxv[tid] = tanhf(acc);
    }
    __syncthreads();
    if (tid < 256) {
        int n = tid & 127, side = tid >> 7;
        const float* sT = side ? s2T : s1T;
        const float* cx = &ctxv[side * 32];
        float acc = 0.f;
        for (int k = 0; k < F3; ++k) acc += sT[k * ST + n] * cx[k];
        av[tid] = sigmoidf(acc);
    }
    __syncthreads();
    {
        int col = tid & 63, chunk = tid >> 6;
        int side = col >> 5;
        const float* sT = side ? &s2T[(col - 32) * ST] : &s1T[col * ST];
        const float* a = &av[side * 128];
        float s = 0.f;
        int nb = chunk * 16;
        for (int n = 0; n < 16; ++n) s += a[nb + n] * sT[nb + n];
        pmean[chunk * 64 + col] = s;
    }
    __syncthreads();
    if (tid < 64) {
        float s = 0.f;
        for (int c = 0; c < 8; ++c) s += pmean[c * 64 + tid];
        ev[tid] = s;
    }
    __syncthreads();

    // ---- tensor network: partials over i ----
    {
        int k = tid & 15, i = tid >> 4;  // i in 0..31
        float e1i = ev[i];
        float acc = 0.f;
        for (int j = 0; j < F3; ++j) acc += ev[32 + j] * tW[(i * F3 + j) * TN + k];
        ptens[i * 16 + k] = e1i * acc;
    }
    __syncthreads();
    if (tid < TN) {
        float acc = tbias[tid];
        for (int i = 0; i < 32; ++i) acc += ptens[i * 16 + tid];
        for (int i = 0; i < F3; ++i) acc += ev[i] * tblk[tid * 2 * F3 + i];
        for (int j = 0; j < F3; ++j) acc += ev[32 + j] * tblk[tid * 2 * F3 + F3 + j];
        feat[tid] = fmaxf(acc, 0.f);
    } else if (tid < TN + BINS) {
        int b = tid - TN;
        int s = 0;
        for (int c = 0; c < 16; ++c) s += bins2[c * 16 + b];
        feat[tid] = (float)s * (1.f / (NPG * NPG));
    }
    __syncthreads();
    if (tid < 16) {
        float acc = sb1[tid];
        for (int i = 0; i < TN + BINS; ++i) acc += feat[i] * sW1[i * 16 + tid];
        hv[tid] = fmaxf(acc, 0.f);
    }
    __syncthreads();
    if (tid == 0) {
        float acc = sb2[0];
        for (int j = 0; j < 16; ++j) acc += hv[j] * sW2[j];
        outp[g] = sigmoidf(acc);
    }
}

// ---------------- launch ----------------
extern "C" void kernel_launch(void* const* d_in, const int* in_sizes, int n_in,
                              void* d_out, int out_size, void* d_ws, size_t ws_size,
                              hipStream_t stream) {
    const float* x1   = (const float*)d_in[0];
    const int*   ei1  = (const int*)d_in[1];
    const float* x2   = (const float*)d_in[3];
    const int*   ei2  = (const int*)d_in[4];
    const float* W1   = (const float*)d_in[6];
    const float* b1   = (const float*)d_in[7];
    const float* W2   = (const float*)d_in[8];
    const float* b2   = (const float*)d_in[9];
    const float* W3   = (const float*)d_in[10];
    const float* b3   = (const float*)d_in[11];
    const float* attW = (const float*)d_in[12];
    const float* tW   = (const float*)d_in[13];
    const float* tblk = (const float*)d_in[14];
    const float* tbias= (const float*)d_in[15];
    const float* sW1  = (const float*)d_in[16];
    const float* sb1  = (const float*)d_in[17];
    const float* sW2  = (const float*)d_in[18];
    const float* sb2  = (const float*)d_in[19];
    float* out = (float*)d_out;

    const int* src1 = ei1;            const int* dst1 = ei1 + N_EDGES;
    const int* src2 = ei2;            const int* dst2 = ei2 + N_EDGES;

    float* bufA = (float*)d_ws;                       // N2*64  (16MB)
    float* bufB = bufA + (size_t)N2 * 64;             // N2*128 (32MB)
    float* dt   = bufB + (size_t)N2 * 128;            // N2*32  (8MB)
    float* dinv = dt + (size_t)N2 * F3;               // N2
    int*   cnt  = (int*)(dinv + N2);                  // N2
    int*   rowp = cnt + N2;                           // N2+1 (pad 16)
    int*   curs = rowp + N2 + 16;                     // N2
    int*   esrc = curs + N2;                          // E2 (4MB)

    // CSR build (merged sides)
    zero_int<<<N2 / 256, 256, 0, stream>>>(cnt, N2);
    csr_count2<<<E2 / 256, 256, 0, stream>>>(dst1, dst2, cnt);
    scan_k<<<1, 1024, 0, stream>>>(cnt, rowp, curs, dinv);
    csr_scatter2<<<E2 / 256, 256, 0, stream>>>(src1, dst1, src2, dst2, curs, esrc);

    // layer 1: (A~ x) @ W1 + b1, relu
    agg_gather_x<<<N2 / 4, 256, 0, stream>>>(x1, x2, rowp, esrc, dinv, bufA);
    mm_tiled<F_IN, F1, 32, true, true><<<N2 / 32, 256, 0, stream>>>(bufA, W1, b1, bufB);

    // layer 2: A~ (h1 @ W2) + b2, relu
    mm_tiled<F1, F2, 32, false, false><<<N2 / 32, 256, 0, stream>>>(bufB, W2, nullptr, bufA);
    agg_gather<F2, true, true><<<N2 * F2 / 256, 256, 0, stream>>>(bufA, rowp, esrc, dinv, b2, bufB);

    // layer 3: A~ (h2 @ W3) + b3
    mm_tiled<F2, F3, 128, false, false><<<N2 / 128, 256, 0, stream>>>(bufB, W3, nullptr, bufA);
    agg_gather<F3, true, false><<<N2 * F3 / 256, 256, 0, stream>>>(bufA, rowp, esrc, dinv, b3, dt);

    post_kernel<<<NGRAPH, 512, 0, stream>>>(dt, attW, tW, tblk, tbias,
                                            sW1, sb1, sW2, sb2, out);
}

// Round 6
// 185.309 us; speedup vs baseline: 5.9176x; 2.1458x over previous
//
#include <hip/hip_runtime.h>
#include <hip/hip_bf16.h>

// Problem constants (fixed by the reference harness)
#define N_NODES 32768
#define N_EDGES 524288
#define NGRAPH  256
#define NPG     128
#define EPG     2048     // edges per graph (DEG=16)
#define F_IN    64
#define F1      128
#define F2      64
#define F3      32
#define TN      16
#define BINS    16
#define XS      129      // padded stride for transposed feature buffers [F][XS]
#define ST      132      // padded stride for post-phase score operands

// LDS pool layout (bytes)
#define OFF_BIG   0                     // 128*129*4 = 66048 : xsT -> h1T -> h2T -> s1T|s2T
#define OFF_XA    66048                 // 64*129*4  = 33024 : xaT -> tT -> uT -> lhist
#define OFF_WL    99072                 // 4096*4    = 16384 : W chunk stage -> post smalls
#define OFF_CNT   115456                // 128*4
#define OFF_ROWP  115968                // 132*4
#define OFF_CURS  116496                // 128*4
#define OFF_DINV  117008                // 128*4
#define OFF_LSRC  117520                // 2048 (uint8 local src ids)
#define OFF_DT    119568                // 2*128*32*4 = 32768 : dt1, dt2 (persist to post)
#define POOL_BYTES 152336               // 148.8 KB < 160 KB

__device__ __forceinline__ float sigmoidf(float x) { return 1.f / (1.f + expf(-x)); }

// ---- dense mm on LDS-transposed features: o[n][c] = sum_k xT[k][n] * W[k][c] ----
template<int FIN, int FOUT, bool BIAS, bool RELU>
__device__ __forceinline__ void mm_lds(const float* __restrict__ xT,
                                       const float* __restrict__ Wg,
                                       const float* __restrict__ bg,
                                       float* __restrict__ oT,
                                       float* __restrict__ wl, int tid) {
    constexpr int CX = FOUT / 8;                       // col groups (2x float4, split halves)
    constexpr int R  = FOUT / 32;                      // rows per thread
    constexpr int KC = (FIN * FOUT > 4096) ? (4096 / FOUT) : FIN;  // W rows per 16KB chunk
    const int cx = tid % CX, ry = tid / CX;
    const int c1 = cx * 4, c2 = FOUT / 2 + cx * 4;
    const int r0 = ry * R;
    float acc[R][8];
#pragma unroll
    for (int r = 0; r < R; ++r)
#pragma unroll
        for (int j = 0; j < 8; ++j) acc[r][j] = 0.f;

    for (int k0 = 0; k0 < FIN; k0 += KC) {
        __syncthreads();                               // wl safe to overwrite
        for (int i = tid * 4; i < KC * FOUT; i += 2048)
            *(float4*)&wl[i] = *(const float4*)&Wg[k0 * FOUT + i];
        __syncthreads();
#pragma unroll 4
        for (int kk = 0; kk < KC; ++kk) {
            const float4 wa = *(const float4*)&wl[kk * FOUT + c1];
            const float4 wb = *(const float4*)&wl[kk * FOUT + c2];
            const float* xp = &xT[(k0 + kk) * XS + r0];
            float xr[R];
#pragma unroll
            for (int r = 0; r < R; ++r) xr[r] = xp[r];
#pragma unroll
            for (int r = 0; r < R; ++r) {
                acc[r][0] += xr[r] * wa.x;
                acc[r][1] += xr[r] * wa.y;
                acc[r][2] += xr[r] * wa.z;
                acc[r][3] += xr[r] * wa.w;
                acc[r][4] += xr[r] * wb.x;
                acc[r][5] += xr[r] * wb.y;
                acc[r][6] += xr[r] * wb.z;
                acc[r][7] += xr[r] * wb.w;
            }
        }
    }
#pragma unroll
    for (int r = 0; r < R; ++r)
#pragma unroll
        for (int j = 0; j < 4; ++j) {
            float v1 = acc[r][j]     + (BIAS ? bg[c1 + j] : 0.f);
            float v2 = acc[r][4 + j] + (BIAS ? bg[c2 + j] : 0.f);
            if (RELU) { v1 = fmaxf(v1, 0.f); v2 = fmaxf(v2, 0.f); }
            oT[(c1 + j) * XS + r0 + r] = v1;
            oT[(c2 + j) * XS + r0 + r] = v2;
        }
}

// ---- GCN aggregate from LDS: out[n][c] = dinv[n]*(sum_j dinv[s_j]*in[s_j][c] + dinv[n]*in[n][c]) ----
template<int F, bool BIAS, bool RELU, bool TOUT>
__device__ __forceinline__ void agg_lds(const float* __restrict__ inT,
                                        float* __restrict__ out,
                                        const int* __restrict__ rowp,
                                        const unsigned char* __restrict__ lsrc,
                                        const float* __restrict__ dinv,
                                        const float* __restrict__ bg, int tid) {
    constexpr int G = 512 / F;
    const int c = tid % F;
    const int gi = tid / F;
    for (int n = gi; n < NPG; n += G) {
        const int r1 = rowp[n + 1];
        const float di = dinv[n];
        float acc = di * inT[c * XS + n];              // self-loop term (x di below)
        for (int j = rowp[n]; j < r1; ++j) {
            const int s = lsrc[j];
            acc += dinv[s] * inT[c * XS + s];
        }
        acc *= di;
        if (BIAS) acc += bg[c];
        if (RELU) acc = fmaxf(acc, 0.f);
        if (TOUT) out[c * XS + n] = acc;
        else      out[n * F + c] = acc;
    }
}

// ---- the whole network: one block per graph pair ----
__global__ __launch_bounds__(512, 1) void genn_mega(
    const float* __restrict__ x1, const int* __restrict__ ei1,
    const float* __restrict__ x2, const int* __restrict__ ei2,
    const float* __restrict__ W1, const float* __restrict__ b1,
    const float* __restrict__ W2, const float* __restrict__ b2,
    const float* __restrict__ W3, const float* __restrict__ b3,
    const float* __restrict__ attW, const float* __restrict__ tW,
    const float* __restrict__ tblk, const float* __restrict__ tbias,
    const float* __restrict__ sW1, const float* __restrict__ sb1,
    const float* __restrict__ sW2, const float* __restrict__ sb2,
    float* __restrict__ outp) {
    __shared__ __align__(16) char pool[POOL_BYTES];
    float* big  = (float*)(pool + OFF_BIG);
    float* xa   = (float*)(pool + OFF_XA);
    float* wl   = (float*)(pool + OFF_WL);
    int*   cnt  = (int*)(pool + OFF_CNT);
    int*   rowp = (int*)(pool + OFF_ROWP);
    int*   curs = (int*)(pool + OFF_CURS);
    float* dinv = (float*)(pool + OFF_DINV);
    unsigned char* lsrc = (unsigned char*)(pool + OFF_LSRC);
    float* dtb  = (float*)(pool + OFF_DT);

    const int g = blockIdx.x;
    const int tid = threadIdx.x;

    for (int side = 0; side < 2; ++side) {
        const float* xg  = (side ? x2 : x1) + (size_t)g * NPG * F_IN;
        const int* eib   = side ? ei2 : ei1;
        const int* srcg  = eib + (size_t)g * EPG;
        const int* dstg  = eib + N_EDGES + (size_t)g * EPG;
        const int nb = g * NPG;
        float* dts = dtb + side * (NPG * F3);

        // ---- local CSR build ----
        if (tid < NPG) cnt[tid] = 0;
        __syncthreads();
#pragma unroll
        for (int it = 0; it < EPG / 512; ++it)
            atomicAdd(&cnt[dstg[it * 512 + tid] - nb], 1);
        __syncthreads();
        if (tid < NPG) dinv[tid] = rsqrtf((float)cnt[tid] + 1.0f);
        __syncthreads();
        // Hillis-Steele inclusive scan of cnt (in place)
        for (int st = 1; st < NPG; st <<= 1) {
            int v = 0;
            if (tid < NPG && tid >= st) v = cnt[tid - st];
            __syncthreads();
            if (tid < NPG) cnt[tid] += v;
            __syncthreads();
        }
        if (tid < NPG) rowp[tid + 1] = cnt[tid];
        if (tid == 0) rowp[0] = 0;
        __syncthreads();
        if (tid < NPG) curs[tid] = rowp[tid];
        __syncthreads();
#pragma unroll
        for (int it = 0; it < EPG / 512; ++it) {
            const int e = it * 512 + tid;
            const int d = dstg[e] - nb;
            const int s = srcg[e] - nb;
            const int p = atomicAdd(&curs[d], 1);
            lsrc[p] = (unsigned char)s;
        }
        // ---- stage x transposed into big (disjoint from CSR writes) ----
#pragma unroll
        for (int it = 0; it < 4; ++it) {
            const int idx = (it * 512 + tid) * 4;
            const float4 v = *(const float4*)&xg[idx];
            const int n = idx >> 6, c = idx & 63;
            big[(c + 0) * XS + n] = v.x;
            big[(c + 1) * XS + n] = v.y;
            big[(c + 2) * XS + n] = v.z;
            big[(c + 3) * XS + n] = v.w;
        }
        __syncthreads();

        // layer 1: (A~ x) @ W1 + b1, relu
        agg_lds<F_IN, false, false, true>(big, xa, rowp, lsrc, dinv, nullptr, tid);
        __syncthreads();
        mm_lds<F_IN, F1, true, true>(xa, W1, b1, big, wl, tid);       // h1T -> big
        __syncthreads();
        // layer 2: A~ (h1 @ W2) + b2, relu
        mm_lds<F1, F2, false, false>(big, W2, nullptr, xa, wl, tid);  // tT -> xa
        __syncthreads();
        agg_lds<F2, true, true, true>(xa, big, rowp, lsrc, dinv, b2, tid);  // h2T -> big
        __syncthreads();
        // layer 3: A~ (h2 @ W3) + b3
        mm_lds<F2, F3, false, false>(big, W3, nullptr, xa, wl, tid);  // uT -> xa
        __syncthreads();
        agg_lds<F3, true, false, false>(xa, dts, rowp, lsrc, dinv, b3, tid); // dt[n][c]
        __syncthreads();
    }

    // ================= post phase (in-LDS dt1/dt2) =================
    float* s1T = big;
    float* s2T = big + F3 * ST;
    unsigned short* lhist = (unsigned short*)xa;       // 512*17 ushort
    float* red  = wl;          // 16
    float* lohi = wl + 16;     // 2
    float* meanv= wl + 18;     // 64
    float* ctxv = wl + 82;     // 64
    float* ev   = wl + 146;    // 64
    float* feat = wl + 210;    // 32
    float* hv   = wl + 242;    // 16
    float* av   = wl + 258;    // 256
    float* pmean= wl + 514;    // 512
    float* ptens= wl + 1026;   // 512
    int*   bins2= (int*)(wl + 1538); // 256
    const float* dt0 = dtb;
    const float* dt1 = dtb + NPG * F3;

    for (int i = tid; i < NPG * F3; i += 512) {
        const int n = i >> 5, c = i & 31;
        s1T[c * ST + n] = dt0[i];
        s2T[c * ST + n] = dt1[i];
    }
    for (int i = tid; i < 512 * 17 / 2; i += 512) ((unsigned int*)lhist)[i] = 0u;
    __syncthreads();

    // ---- scores once into registers: 4 n-rows x 8 m-cols per thread ----
    const int ny = tid >> 4, mx = tid & 15;
    const int n0 = ny * 4, m0 = mx * 8;
    float sc[4][8];
#pragma unroll
    for (int r = 0; r < 4; ++r)
#pragma unroll
        for (int m = 0; m < 8; ++m) sc[r][m] = 0.f;
#pragma unroll 4
    for (int k = 0; k < F3; ++k) {
        const float4 a4 = *(float4*)&s1T[k * ST + n0];
        const float4 b4 = *(float4*)&s2T[k * ST + m0];
        const float4 c4 = *(float4*)&s2T[k * ST + m0 + 4];
        const float avr[4] = {a4.x, a4.y, a4.z, a4.w};
        const float bv[8] = {b4.x, b4.y, b4.z, b4.w, c4.x, c4.y, c4.z, c4.w};
#pragma unroll
        for (int r = 0; r < 4; ++r)
#pragma unroll
            for (int m = 0; m < 8; ++m) sc[r][m] += avr[r] * bv[m];
    }
    // min/max (raw space; sigmoid monotone)
    float lmin = sc[0][0], lmax = sc[0][0];
#pragma unroll
    for (int r = 0; r < 4; ++r)
#pragma unroll
        for (int m = 0; m < 8; ++m) {
            lmin = fminf(lmin, sc[r][m]);
            lmax = fmaxf(lmax, sc[r][m]);
        }
    for (int off = 32; off; off >>= 1) {
        lmin = fminf(lmin, __shfl_down(lmin, off));
        lmax = fmaxf(lmax, __shfl_down(lmax, off));
    }
    const int wid = tid >> 6;
    if ((tid & 63) == 0) { red[wid] = lmin; red[8 + wid] = lmax; }
    __syncthreads();
    if (tid == 0) {
        float mn = red[0], mxv = red[8];
        for (int w = 1; w < 8; ++w) { mn = fminf(mn, red[w]); mxv = fmaxf(mxv, red[8 + w]); }
        lohi[0] = sigmoidf(mn);
        lohi[1] = sigmoidf(mxv);
    }
    __syncthreads();
    const float lo = lohi[0];
    const float denom = fmaxf(lohi[1] - lo, 1e-12f);

    // ---- histogram into per-thread private counters ----
    {
        unsigned short* lh = &lhist[tid * 17];
#pragma unroll
        for (int r = 0; r < 4; ++r)
#pragma unroll
            for (int m = 0; m < 8; ++m) {
                const float v = sigmoidf(sc[r][m]);
                int bidx = (int)floorf((v - lo) / denom * (float)BINS);
                bidx = min(max(bidx, 0), BINS - 1);
                lh[bidx]++;
            }
    }
    __syncthreads();
    if (tid < 256) {
        const int b = tid & 15, chunk = tid >> 4;
        int s = 0;
        for (int i = 0; i < 32; ++i) s += lhist[(chunk * 32 + i) * 17 + b];
        bins2[chunk * 16 + b] = s;
    }
    __syncthreads();

    // ---- attention pooling ----
    {
        const int col = tid & 63, chunk = tid >> 6;
        const float* sT = (col < 32) ? &s1T[col * ST] : &s2T[(col - 32) * ST];
        float s = 0.f;
        const int nbs = chunk * 16;
        for (int n = 0; n < 16; ++n) s += sT[nbs + n];
        pmean[chunk * 64 + col] = s;
    }
    __syncthreads();
    if (tid < 64) {
        float s = 0.f;
        for (int c = 0; c < 8; ++c) s += pmean[c * 64 + tid];
        meanv[tid] = s * (1.f / NPG);
    }
    __syncthreads();
    if (tid < 64) {
        const int c = tid & 31;
        const float* mv = &meanv[(tid >> 5) * 32];
        float acc = 0.f;
        for (int k = 0; k < F3; ++k) acc += mv[k] * attW[k * F3 + c];
        ctxv[tid] = tanhf(acc);
    }
    __syncthreads();
    if (tid < 256) {
        const int n = tid & 127, side = tid >> 7;
        const float* sT = side ? s2T : s1T;
        const float* cx = &ctxv[side * 32];
        float acc = 0.f;
        for (int k = 0; k < F3; ++k) acc += sT[k * ST + n] * cx[k];
        av[tid] = sigmoidf(acc);
    }
    __syncthreads();
    {
        const int col = tid & 63, chunk = tid >> 6;
        const int side = col >> 5;
        const float* sT = side ? &s2T[(col - 32) * ST] : &s1T[col * ST];
        const float* a = &av[side * 128];
        float s = 0.f;
        const int nbs = chunk * 16;
        for (int n = 0; n < 16; ++n) s += a[nbs + n] * sT[nbs + n];
        pmean[chunk * 64 + col] = s;
    }
    __syncthreads();
    if (tid < 64) {
        float s = 0.f;
        for (int c = 0; c < 8; ++c) s += pmean[c * 64 + tid];
        ev[tid] = s;
    }
    __syncthreads();

    // ---- tensor network ----
    {
        const int k = tid & 15, i = tid >> 4;  // i in 0..31
        const float e1i = ev[i];
        float acc = 0.f;
        for (int j = 0; j < F3; ++j) acc += ev[32 + j] * tW[(i * F3 + j) * TN + k];
        ptens[i * 16 + k] = e1i * acc;
    }
    __syncthreads();
    if (tid < TN) {
        float acc = tbias[tid];
        for (int i = 0; i < 32; ++i) acc += ptens[i * 16 + tid];
        for (int i = 0; i < F3; ++i) acc += ev[i] * tblk[tid * 2 * F3 + i];
        for (int j = 0; j < F3; ++j) acc += ev[32 + j] * tblk[tid * 2 * F3 + F3 + j];
        feat[tid] = fmaxf(acc, 0.f);
    } else if (tid < TN + BINS) {
        const int b = tid - TN;
        int s = 0;
        for (int c = 0; c < 16; ++c) s += bins2[c * 16 + b];
        feat[tid] = (float)s * (1.f / (NPG * NPG));
    }
    __syncthreads();
    if (tid < 16) {
        float acc = sb1[tid];
        for (int i = 0; i < TN + BINS; ++i) acc += feat[i] * sW1[i * 16 + tid];
        hv[tid] = fmaxf(acc, 0.f);
    }
    __syncthreads();
    if (tid == 0) {
        float acc = sb2[0];
        for (int j = 0; j < 16; ++j) acc += hv[j] * sW2[j];
        outp[g] = sigmoidf(acc);
    }
}

// ---------------- launch ----------------
extern "C" void kernel_launch(void* const* d_in, const int* in_sizes, int n_in,
                              void* d_out, int out_size, void* d_ws, size_t ws_size,
                              hipStream_t stream) {
    const float* x1   = (const float*)d_in[0];
    const int*   ei1  = (const int*)d_in[1];
    const float* x2   = (const float*)d_in[3];
    const int*   ei2  = (const int*)d_in[4];
    const float* W1   = (const float*)d_in[6];
    const float* b1   = (const float*)d_in[7];
    const float* W2   = (const float*)d_in[8];
    const float* b2   = (const float*)d_in[9];
    const float* W3   = (const float*)d_in[10];
    const float* b3   = (const float*)d_in[11];
    const float* attW = (const float*)d_in[12];
    const float* tW   = (const float*)d_in[13];
    const float* tblk = (const float*)d_in[14];
    const float* tbias= (const float*)d_in[15];
    const float* sW1  = (const float*)d_in[16];
    const float* sb1  = (const float*)d_in[17];
    const float* sW2  = (const float*)d_in[18];
    const float* sb2  = (const float*)d_in[19];
    float* out = (float*)d_out;
    (void)in_sizes; (void)n_in; (void)out_size; (void)d_ws; (void)ws_size;

    genn_mega<<<NGRAPH, 512, 0, stream>>>(x1, ei1, x2, ei2,
                                          W1, b1, W2, b2, W3, b3,
                                          attW, tW, tblk, tbias,
                                          sW1, sb1, sW2, sb2, out);
}

// Round 7
// 118.733 us; speedup vs baseline: 9.2357x; 1.5607x over previous
//
#include <hip/hip_runtime.h>
#include <hip/hip_bf16.h>
#include <hip/hip_fp16.h>

// Problem constants (fixed by the reference harness)
#define N_NODES 32768
#define N_EDGES 524288
#define NGRAPH  256
#define NPG     128
#define EPG     2048     // edges per graph (DEG=16)
#define F_IN    64
#define F1      128
#define F2      64
#define F3      32
#define TN      16
#define BINS    16
#define XSH     132      // padded stride (f16 elems) for transposed feature tiles

typedef _Float16 f16;
typedef _Float16 f16x4 __attribute__((ext_vector_type(4)));

__device__ __forceinline__ float sigmoidf(float x) { return 1.f / (1.f + expf(-x)); }

// ---- GCN kernel LDS pool (bytes) ----
#define A_BIG   0         // f16 [128][132] = 33792 : xT -> h1T -> h2T
#define A_XA    33792     // f16 [64][132]  = 16896 : aggT -> tT -> uT
#define A_WL    50688     // f32 2048       = 8192  : W chunk stage
#define A_CNT   58880     // int 128
#define A_ROWP  59392     // int 132
#define A_CURS  59936     // int 128
#define A_DINV  60448     // f32 128
#define A_LSRC  60960     // u8  2048
#define A_SH    63008     // f16 [32][132]  = 8448  : dt tile
#define A_POOL  71456

// ---- dense mm on LDS f16 features: oT[c][n] = sum_k xT[k][n] * W[k][c] ----
template<int FIN, int FOUT, bool BIAS, bool RELU>
__device__ __forceinline__ void mm_lds(const f16* __restrict__ xT,
                                       const float* __restrict__ Wg,
                                       const float* __restrict__ bg,
                                       f16* __restrict__ oT,
                                       float* __restrict__ wl, int tid) {
    constexpr int CX = FOUT / 8;                 // col groups (4+4 split halves)
    constexpr int R  = FOUT / 32;                // rows per thread (128*CX/512... = FOUT/32)
    constexpr int KC = (FIN * FOUT > 2048) ? (2048 / FOUT) : FIN;  // W rows per 8KB chunk
    const int cx = tid % CX, ry = tid / CX;
    const int c1 = cx * 4, c2 = FOUT / 2 + cx * 4;
    const int r0 = ry * R;
    float acc[R][8];
#pragma unroll
    for (int r = 0; r < R; ++r)
#pragma unroll
        for (int j = 0; j < 8; ++j) acc[r][j] = 0.f;

    for (int k0 = 0; k0 < FIN; k0 += KC) {
        __syncthreads();                         // wl safe to overwrite
        *(float4*)&wl[tid * 4] = *(const float4*)&Wg[k0 * FOUT + tid * 4];  // KC*FOUT==2048
        __syncthreads();
#pragma unroll 4
        for (int kk = 0; kk < KC; ++kk) {
            const float4 wa = *(const float4*)&wl[kk * FOUT + c1];
            const float4 wb = *(const float4*)&wl[kk * FOUT + c2];
            const f16* xp = &xT[(k0 + kk) * XSH + r0];
            float xr[R];
#pragma unroll
            for (int r = 0; r < R; ++r) xr[r] = (float)xp[r];
#pragma unroll
            for (int r = 0; r < R; ++r) {
                acc[r][0] += xr[r] * wa.x;
                acc[r][1] += xr[r] * wa.y;
                acc[r][2] += xr[r] * wa.z;
                acc[r][3] += xr[r] * wa.w;
                acc[r][4] += xr[r] * wb.x;
                acc[r][5] += xr[r] * wb.y;
                acc[r][6] += xr[r] * wb.z;
                acc[r][7] += xr[r] * wb.w;
            }
        }
    }
#pragma unroll
    for (int r = 0; r < R; ++r)
#pragma unroll
        for (int j = 0; j < 4; ++j) {
            float v1 = acc[r][j]     + (BIAS ? bg[c1 + j] : 0.f);
            float v2 = acc[r][4 + j] + (BIAS ? bg[c2 + j] : 0.f);
            if (RELU) { v1 = fmaxf(v1, 0.f); v2 = fmaxf(v2, 0.f); }
            oT[(c1 + j) * XSH + r0 + r] = (f16)v1;
            oT[(c2 + j) * XSH + r0 + r] = (f16)v2;
        }
}

// ---- GCN aggregate from LDS (transposed in, transposed out) ----
template<int F, bool BIAS, bool RELU>
__device__ __forceinline__ void agg_lds(const f16* __restrict__ inT,
                                        f16* __restrict__ outT,
                                        const int* __restrict__ rowp,
                                        const unsigned char* __restrict__ lsrc,
                                        const float* __restrict__ dinv,
                                        const float* __restrict__ bg, int tid) {
    constexpr int G = 512 / F;
    const int c = tid % F;
    const int gi = tid / F;
    for (int n = gi; n < NPG; n += G) {
        const int r1 = rowp[n + 1];
        const float di = dinv[n];
        float acc = di * (float)inT[c * XSH + n];      // self-loop (x di below)
        for (int j = rowp[n]; j < r1; ++j) {
            const int s = lsrc[j];
            acc += dinv[s] * (float)inT[c * XSH + s];
        }
        acc *= di;
        if (BIAS) acc += bg[c];
        if (RELU) acc = fmaxf(acc, 0.f);
        outT[c * XSH + n] = (f16)acc;
    }
}

// ---- GCN kernel: one block per (graph, side); grid = 512, 2 blocks/CU ----
__global__ __launch_bounds__(512, 4) void gcn_kernel(
    const float* __restrict__ x1, const int* __restrict__ ei1,
    const float* __restrict__ x2, const int* __restrict__ ei2,
    const float* __restrict__ W1, const float* __restrict__ b1,
    const float* __restrict__ W2, const float* __restrict__ b2,
    const float* __restrict__ W3, const float* __restrict__ b3,
    f16* __restrict__ dtg) {
    __shared__ __align__(16) char pool[A_POOL];
    f16*   big  = (f16*)(pool + A_BIG);
    f16*   xa   = (f16*)(pool + A_XA);
    float* wl   = (float*)(pool + A_WL);
    int*   cnt  = (int*)(pool + A_CNT);
    int*   rowp = (int*)(pool + A_ROWP);
    int*   curs = (int*)(pool + A_CURS);
    float* dinv = (float*)(pool + A_DINV);
    unsigned char* lsrc = (unsigned char*)(pool + A_LSRC);
    f16*   sh   = (f16*)(pool + A_SH);

    const int g = blockIdx.x >> 1;
    const int side = blockIdx.x & 1;
    const int tid = threadIdx.x;

    const float* xg = (side ? x2 : x1) + (size_t)g * NPG * F_IN;
    const int* eib  = side ? ei2 : ei1;
    const int* srcg = eib + (size_t)g * EPG;
    const int* dstg = eib + N_EDGES + (size_t)g * EPG;
    const int nb = g * NPG;

    // ---- local CSR build ----
    if (tid < NPG) cnt[tid] = 0;
    __syncthreads();
#pragma unroll
    for (int it = 0; it < EPG / 512; ++it)
        atomicAdd(&cnt[dstg[it * 512 + tid] - nb], 1);
    __syncthreads();
    if (tid < NPG) dinv[tid] = rsqrtf((float)cnt[tid] + 1.0f);
    __syncthreads();
    for (int st = 1; st < NPG; st <<= 1) {       // Hillis-Steele inclusive scan
        int v = 0;
        if (tid < NPG && tid >= st) v = cnt[tid - st];
        __syncthreads();
        if (tid < NPG) cnt[tid] += v;
        __syncthreads();
    }
    if (tid < NPG) rowp[tid + 1] = cnt[tid];
    if (tid == 0) rowp[0] = 0;
    __syncthreads();
    if (tid < NPG) curs[tid] = rowp[tid];
    __syncthreads();
#pragma unroll
    for (int it = 0; it < EPG / 512; ++it) {
        const int e = it * 512 + tid;
        const int d = dstg[e] - nb;
        const int s = srcg[e] - nb;
        const int p = atomicAdd(&curs[d], 1);
        lsrc[p] = (unsigned char)s;
    }
    // ---- stage x transposed f16 into big (disjoint from CSR regions) ----
#pragma unroll
    for (int it = 0; it < 4; ++it) {
        const int idx = (it * 512 + tid) * 4;
        const float4 v = *(const float4*)&xg[idx];
        const int n = idx >> 6, c = idx & 63;
        big[(c + 0) * XSH + n] = (f16)v.x;
        big[(c + 1) * XSH + n] = (f16)v.y;
        big[(c + 2) * XSH + n] = (f16)v.z;
        big[(c + 3) * XSH + n] = (f16)v.w;
    }
    __syncthreads();

    // layer 1: (A~ x) @ W1 + b1, relu
    agg_lds<F_IN, false, false>(big, xa, rowp, lsrc, dinv, nullptr, tid);
    __syncthreads();
    mm_lds<F_IN, F1, true, true>(xa, W1, b1, big, wl, tid);     // h1T -> big
    __syncthreads();
    // layer 2: A~ (h1 @ W2) + b2, relu
    mm_lds<F1, F2, false, false>(big, W2, nullptr, xa, wl, tid); // tT -> xa
    __syncthreads();
    agg_lds<F2, true, true>(xa, big, rowp, lsrc, dinv, b2, tid); // h2T -> big
    __syncthreads();
    // layer 3: A~ (h2 @ W3) + b3
    mm_lds<F2, F3, false, false>(big, W3, nullptr, xa, wl, tid); // uT -> xa
    __syncthreads();
    agg_lds<F3, true, false>(xa, sh, rowp, lsrc, dinv, b3, tid); // dtT -> sh
    __syncthreads();

    // ---- dump dt tile [32][128] to global ----
    f16* dst = dtg + (size_t)(side * NGRAPH + g) * (F3 * NPG);
#pragma unroll
    for (int it = 0; it < 2; ++it) {
        const int i = (it * 512 + tid) * 4;
        const int c = i >> 7, n = i & 127;
        *(f16x4*)&dst[i] = *(const f16x4*)&sh[c * XSH + n];
    }
}

// ---- post kernel LDS pool ----
#define B_S1    0                      // f16 [32][132] = 8448
#define B_S2    8448                   // f16 [32][132] = 8448
#define B_LH    16896                  // ushort 512*17 = 17408
#define B_WL    34304                  // f32 1794 -> 7184
#define B_POOL  41488

__global__ __launch_bounds__(512) void post_kernel(
    const f16* __restrict__ dtg,
    const float* __restrict__ attW, const float* __restrict__ tW,
    const float* __restrict__ tblk, const float* __restrict__ tbias,
    const float* __restrict__ sW1, const float* __restrict__ sb1,
    const float* __restrict__ sW2, const float* __restrict__ sb2,
    float* __restrict__ outp) {
    __shared__ __align__(16) char pool[B_POOL];
    f16* s1T = (f16*)(pool + B_S1);
    f16* s2T = (f16*)(pool + B_S2);
    unsigned short* lhist = (unsigned short*)(pool + B_LH);
    float* wl   = (float*)(pool + B_WL);
    float* red  = wl;          // 16
    float* lohi = wl + 16;     // 2
    float* meanv= wl + 18;     // 64
    float* ctxv = wl + 82;     // 64
    float* ev   = wl + 146;    // 64
    float* feat = wl + 210;    // 32
    float* hv   = wl + 242;    // 16
    float* av   = wl + 258;    // 256
    float* pmean= wl + 514;    // 512
    float* ptens= wl + 1026;   // 512
    int*   bins2= (int*)(wl + 1538); // 256

    const int g = blockIdx.x;
    const int tid = threadIdx.x;
    const f16* dt0 = dtg + (size_t)g * (F3 * NPG);
    const f16* dt1 = dtg + (size_t)(NGRAPH + g) * (F3 * NPG);

    // stage dt tiles (linear [32][128] -> stride-132)
#pragma unroll
    for (int it = 0; it < 2; ++it) {
        const int i = (it * 512 + tid) * 4;
        const int c = i >> 7, n = i & 127;
        *(f16x4*)&s1T[c * XSH + n] = *(const f16x4*)&dt0[i];
        *(f16x4*)&s2T[c * XSH + n] = *(const f16x4*)&dt1[i];
    }
    for (int i = tid; i < 512 * 17 / 2; i += 512) ((unsigned int*)lhist)[i] = 0u;
    __syncthreads();

    // ---- scores once into registers: 4 n-rows x 8 m-cols per thread ----
    const int ny = tid >> 4, mx = tid & 15;
    const int n0 = ny * 4, m0 = mx * 8;
    float sc[4][8];
#pragma unroll
    for (int r = 0; r < 4; ++r)
#pragma unroll
        for (int m = 0; m < 8; ++m) sc[r][m] = 0.f;
#pragma unroll 4
    for (int k = 0; k < F3; ++k) {
        const f16x4 a4 = *(const f16x4*)&s1T[k * XSH + n0];
        const f16x4 b4 = *(const f16x4*)&s2T[k * XSH + m0];
        const f16x4 c4 = *(const f16x4*)&s2T[k * XSH + m0 + 4];
        float avr[4], bv[8];
#pragma unroll
        for (int r = 0; r < 4; ++r) avr[r] = (float)a4[r];
#pragma unroll
        for (int m = 0; m < 4; ++m) { bv[m] = (float)b4[m]; bv[4 + m] = (float)c4[m]; }
#pragma unroll
        for (int r = 0; r < 4; ++r)
#pragma unroll
            for (int m = 0; m < 8; ++m) sc[r][m] += avr[r] * bv[m];
    }
    // min/max (raw space; sigmoid monotone)
    float lmin = sc[0][0], lmax = sc[0][0];
#pragma unroll
    for (int r = 0; r < 4; ++r)
#pragma unroll
        for (int m = 0; m < 8; ++m) {
            lmin = fminf(lmin, sc[r][m]);
            lmax = fmaxf(lmax, sc[r][m]);
        }
    for (int off = 32; off; off >>= 1) {
        lmin = fminf(lmin, __shfl_down(lmin, off));
        lmax = fmaxf(lmax, __shfl_down(lmax, off));
    }
    const int wid = tid >> 6;
    if ((tid & 63) == 0) { red[wid] = lmin; red[8 + wid] = lmax; }
    __syncthreads();
    if (tid == 0) {
        float mn = red[0], mxv = red[8];
        for (int w = 1; w < 8; ++w) { mn = fminf(mn, red[w]); mxv = fmaxf(mxv, red[8 + w]); }
        lohi[0] = sigmoidf(mn);
        lohi[1] = sigmoidf(mxv);
    }
    __syncthreads();
    const float lo = lohi[0];
    const float denom = fmaxf(lohi[1] - lo, 1e-12f);

    // ---- histogram into per-thread private counters ----
    {
        unsigned short* lh = &lhist[tid * 17];
#pragma unroll
        for (int r = 0; r < 4; ++r)
#pragma unroll
            for (int m = 0; m < 8; ++m) {
                const float v = sigmoidf(sc[r][m]);
                int bidx = (int)floorf((v - lo) / denom * (float)BINS);
                bidx = min(max(bidx, 0), BINS - 1);
                lh[bidx]++;
            }
    }
    __syncthreads();
    if (tid < 256) {
        const int b = tid & 15, chunk = tid >> 4;
        int s = 0;
        for (int i = 0; i < 32; ++i) s += lhist[(chunk * 32 + i) * 17 + b];
        bins2[chunk * 16 + b] = s;
    }
    __syncthreads();

    // ---- attention pooling ----
    {
        const int col = tid & 63, chunk = tid >> 6;
        const f16* sT = (col < 32) ? &s1T[col * XSH] : &s2T[(col - 32) * XSH];
        float s = 0.f;
        const int nbs = chunk * 16;
        for (int n = 0; n < 16; ++n) s += (float)sT[nbs + n];
        pmean[chunk * 64 + col] = s;
    }
    __syncthreads();
    if (tid < 64) {
        float s = 0.f;
        for (int c = 0; c < 8; ++c) s += pmean[c * 64 + tid];
        meanv[tid] = s * (1.f / NPG);
    }
    __syncthreads();
    if (tid < 64) {
        const int c = tid & 31;
        const float* mv = &meanv[(tid >> 5) * 32];
        float acc = 0.f;
        for (int k = 0; k < F3; ++k) acc += mv[k] * attW[k * F3 + c];
        ctxv[tid] = tanhf(acc);
    }
    __syncthreads();
    if (tid < 256) {
        const int n = tid & 127, side = tid >> 7;
        const f16* sT = side ? s2T : s1T;
        const float* cx = &ctxv[side * 32];
        float acc = 0.f;
        for (int k = 0; k < F3; ++k) acc += (float)sT[k * XSH + n] * cx[k];
        av[tid] = sigmoidf(acc);
    }
    __syncthreads();
    {
        const int col = tid & 63, chunk = tid >> 6;
        const int side = col >> 5;
        const f16* sT = side ? &s2T[(col - 32) * XSH] : &s1T[col * XSH];
        const float* a = &av[side * 128];
        float s = 0.f;
        const int nbs = chunk * 16;
        for (int n = 0; n < 16; ++n) s += a[nbs + n] * (float)sT[nbs + n];
        pmean[chunk * 64 + col] = s;
    }
    __syncthreads();
    if (tid < 64) {
        float s = 0.f;
        for (int c = 0; c < 8; ++c) s += pmean[c * 64 + tid];
        ev[tid] = s;
    }
    __syncthreads();

    // ---- tensor network ----
    {
        const int k = tid & 15, i = tid >> 4;  // i in 0..31
        const float e1i = ev[i];
        float acc = 0.f;
        for (int j = 0; j < F3; ++j) acc += ev[32 + j] * tW[(i * F3 + j) * TN + k];
        ptens[i * 16 + k] = e1i * acc;
    }
    __syncthreads();
    if (tid < TN) {
        float acc = tbias[tid];
        for (int i = 0; i < 32; ++i) acc += ptens[i * 16 + tid];
        for (int i = 0; i < F3; ++i) acc += ev[i] * tblk[tid * 2 * F3 + i];
        for (int j = 0; j < F3; ++j) acc += ev[32 + j] * tblk[tid * 2 * F3 + F3 + j];
        feat[tid] = fmaxf(acc, 0.f);
    } else if (tid < TN + BINS) {
        const int b = tid - TN;
        int s = 0;
        for (int c = 0; c < 16; ++c) s += bins2[c * 16 + b];
        feat[tid] = (float)s * (1.f / (NPG * NPG));
    }
    __syncthreads();
    if (tid < 16) {
        float acc = sb1[tid];
        for (int i = 0; i < TN + BINS; ++i) acc += feat[i] * sW1[i * 16 + tid];
        hv[tid] = fmaxf(acc, 0.f);
    }
    __syncthreads();
    if (tid == 0) {
        float acc = sb2[0];
        for (int j = 0; j < 16; ++j) acc += hv[j] * sW2[j];
        outp[g] = sigmoidf(acc);
    }
}

// ---------------- launch ----------------
extern "C" void kernel_launch(void* const* d_in, const int* in_sizes, int n_in,
                              void* d_out, int out_size, void* d_ws, size_t ws_size,
                              hipStream_t stream) {
    const float* x1   = (const float*)d_in[0];
    const int*   ei1  = (const int*)d_in[1];
    const float* x2   = (const float*)d_in[3];
    const int*   ei2  = (const int*)d_in[4];
    const float* W1   = (const float*)d_in[6];
    const float* b1   = (const float*)d_in[7];
    const float* W2   = (const float*)d_in[8];
    const float* b2   = (const float*)d_in[9];
    const float* W3   = (const float*)d_in[10];
    const float* b3   = (const float*)d_in[11];
    const float* attW = (const float*)d_in[12];
    const float* tW   = (const float*)d_in[13];
    const float* tblk = (const float*)d_in[14];
    const float* tbias= (const float*)d_in[15];
    const float* sW1  = (const float*)d_in[16];
    const float* sb1  = (const float*)d_in[17];
    const float* sW2  = (const float*)d_in[18];
    const float* sb2  = (const float*)d_in[19];
    float* out = (float*)d_out;
    (void)in_sizes; (void)n_in; (void)out_size; (void)ws_size;

    f16* dtg = (f16*)d_ws;   // [2][256][32][128] f16 = 4MB

    gcn_kernel<<<NGRAPH * 2, 512, 0, stream>>>(x1, ei1, x2, ei2,
                                               W1, b1, W2, b2, W3, b3, dtg);
    post_kernel<<<NGRAPH, 512, 0, stream>>>(dtg, attW, tW, tblk, tbias,
                                            sW1, sb1, sW2, sb2, out);
}

// Round 8
// 51.505 us; speedup vs baseline: 21.2907x; 2.3053x over previous
//
#include <hip/hip_runtime.h>
#include <hip/hip_bf16.h>
#include <hip/hip_fp16.h>

// Problem constants (fixed by the reference harness)
#define N_NODES 32768
#define N_EDGES 524288
#define NGRAPH  256
#define NPG     128
#define EPG     2048     // edges per graph (DEG=16)
#define F_IN    64
#define F1      128
#define F2      64
#define F3      32
#define TN      16
#define BINS    16
#define XSH     132      // padded stride (f16) for post-phase tiles

typedef _Float16 f16;
typedef _Float16 f16x4 __attribute__((ext_vector_type(4)));
typedef _Float16 f16x8 __attribute__((ext_vector_type(8)));
typedef float    f32x4 __attribute__((ext_vector_type(4)));

__device__ __forceinline__ float sigmoidf(float x) { return 1.f / (1.f + expf(-x)); }

// ---- GCN kernel LDS pool (bytes); total 75792 -> 2 blocks/CU ----
#define A_P     0         // f16 [128][136] = 34816 : h1
#define A_Q     34816     // f16 [128][72]  = 18432 : x16 -> Wt1 -> Wt2 -> h2
#define A_R     53248     // f16 [128][72]  = 18432 : a1 -> t2 -> Wt3|t3
#define A_CNT   71680     // int 128
#define A_ROWP  72192     // int 132
#define A_CURS  72720     // int 128
#define A_DINV  73232     // f32 128
#define A_LSRC  73744     // u8  2048
#define A_POOL  75792

#define SP  72            // stride for K<=64 feature tiles (f16; 144B, 16B-aligned)
#define SP1 136           // stride for K=128 tile (h1)
#define SP3 40            // stride for t3 tile

// ---- stage W transposed f16: wt[c][k] = W[k][c] ----
template<int K, int N, int WTS>
__device__ __forceinline__ void stage_wt(const float* __restrict__ Wg,
                                         f16* __restrict__ wt, int tid) {
    for (int i = tid; i < K * N; i += 512)
        wt[(i % N) * WTS + (i / N)] = (f16)Wg[i];
}

// ---- MFMA matmul: out[n][c] = relu(sum_k in[n][k] * W[k][c] + b[c]) ----
// in: [128][INS] f16, wt: [N][WTS] f16 (transposed W), out: [128][OUTS] f16.
template<int K, int N, int INS, int WTS, int OUTS, bool BIAS, bool RELU>
__device__ __forceinline__ void mm_mfma(const f16* __restrict__ in,
                                        const f16* __restrict__ wt,
                                        const float* __restrict__ bg,
                                        f16* __restrict__ out, int tid) {
    const int wv = tid >> 6, lane = tid & 63;
    const int col = lane & 15, g = lane >> 4;
    const int rowa = wv * 16 + col;
    constexpr int NT = N / 16, KS = K / 32;
    f32x4 acc[NT];
#pragma unroll
    for (int nt = 0; nt < NT; ++nt) {
        const float b = BIAS ? bg[nt * 16 + col] : 0.f;
        acc[nt] = (f32x4){b, b, b, b};
    }
#pragma unroll
    for (int ks = 0; ks < KS; ++ks) {
        const f16x8 a = *(const f16x8*)&in[rowa * INS + ks * 32 + g * 8];
#pragma unroll
        for (int nt = 0; nt < NT; ++nt) {
            const f16x8 b = *(const f16x8*)&wt[(nt * 16 + col) * WTS + ks * 32 + g * 8];
            acc[nt] = __builtin_amdgcn_mfma_f32_16x16x32_f16(a, b, acc[nt], 0, 0, 0);
        }
    }
#pragma unroll
    for (int nt = 0; nt < NT; ++nt)
#pragma unroll
        for (int j = 0; j < 4; ++j) {
            float v = acc[nt][j];
            if (RELU) v = fmaxf(v, 0.f);
            out[(wv * 16 + g * 4 + j) * OUTS + nt * 16 + col] = (f16)v;
        }
}

// ---- GCN aggregate, vectorized: 4 threads/node, F/4 channels each ----
template<int F, int INS, int OUTS, bool BIAS, bool RELU>
__device__ __forceinline__ void agg_lds(const f16* __restrict__ in,
                                        f16* __restrict__ out,
                                        const int* __restrict__ rowp,
                                        const unsigned char* __restrict__ lsrc,
                                        const float* __restrict__ dinv,
                                        const float* __restrict__ bg, int tid) {
    constexpr int CPT = F / 4;
    const int n = tid >> 2, c0 = (tid & 3) * CPT;
    const float di = dinv[n];
    float acc[CPT];
    {
        const f16* p = &in[n * INS + c0];
#pragma unroll
        for (int ch = 0; ch < CPT / 8; ++ch) {
            const f16x8 v = *(const f16x8*)(p + ch * 8);
#pragma unroll
            for (int q = 0; q < 8; ++q) acc[ch * 8 + q] = di * (float)v[q];
        }
    }
    const int r1 = rowp[n + 1];
    for (int j = rowp[n]; j < r1; ++j) {
        const int s = lsrc[j];
        const float w = dinv[s];
        const f16* p = &in[s * INS + c0];
#pragma unroll
        for (int ch = 0; ch < CPT / 8; ++ch) {
            const f16x8 v = *(const f16x8*)(p + ch * 8);
#pragma unroll
            for (int q = 0; q < 8; ++q) acc[ch * 8 + q] += w * (float)v[q];
        }
    }
#pragma unroll
    for (int ch = 0; ch < CPT / 8; ++ch) {
        f16x8 o;
#pragma unroll
        for (int q = 0; q < 8; ++q) {
            float v = di * acc[ch * 8 + q];
            if (BIAS) v += bg[c0 + ch * 8 + q];
            if (RELU) v = fmaxf(v, 0.f);
            o[q] = (f16)v;
        }
        *(f16x8*)&out[n * OUTS + c0 + ch * 8] = o;
    }
}

// ---- final aggregate (F=32) writing [c][n] tile to global ----
__device__ __forceinline__ void agg_out(const f16* __restrict__ in,
                                        f16* __restrict__ dst,   // + (side*NGRAPH+g)*4096
                                        const int* __restrict__ rowp,
                                        const unsigned char* __restrict__ lsrc,
                                        const float* __restrict__ dinv,
                                        const float* __restrict__ bg, int tid) {
    const int n = tid >> 2, c0 = (tid & 3) * 8;
    const float di = dinv[n];
    float acc[8];
    {
        const f16x8 v = *(const f16x8*)&in[n * SP3 + c0];
#pragma unroll
        for (int q = 0; q < 8; ++q) acc[q] = di * (float)v[q];
    }
    const int r1 = rowp[n + 1];
    for (int j = rowp[n]; j < r1; ++j) {
        const int s = lsrc[j];
        const float w = dinv[s];
        const f16x8 v = *(const f16x8*)&in[s * SP3 + c0];
#pragma unroll
        for (int q = 0; q < 8; ++q) acc[q] += w * (float)v[q];
    }
#pragma unroll
    for (int q = 0; q < 8; ++q)
        dst[(c0 + q) * NPG + n] = (f16)(di * acc[q] + bg[c0 + q]);
}

// ---- GCN kernel: one block per (graph, side); grid = 512, 2 blocks/CU ----
__global__ __launch_bounds__(512, 4) void gcn_kernel(
    const float* __restrict__ x1, const int* __restrict__ ei1,
    const float* __restrict__ x2, const int* __restrict__ ei2,
    const float* __restrict__ W1, const float* __restrict__ b1,
    const float* __restrict__ W2, const float* __restrict__ b2,
    const float* __restrict__ W3, const float* __restrict__ b3,
    f16* __restrict__ dtg) {
    __shared__ __align__(16) char pool[A_POOL];
    f16*   P    = (f16*)(pool + A_P);
    f16*   Q    = (f16*)(pool + A_Q);
    f16*   R    = (f16*)(pool + A_R);
    int*   cnt  = (int*)(pool + A_CNT);
    int*   rowp = (int*)(pool + A_ROWP);
    int*   curs = (int*)(pool + A_CURS);
    float* dinv = (float*)(pool + A_DINV);
    unsigned char* lsrc = (unsigned char*)(pool + A_LSRC);
    f16*   t3   = (f16*)(pool + A_R + 4608);

    const int g = blockIdx.x >> 1;
    const int side = blockIdx.x & 1;
    const int tid = threadIdx.x;

    const float* xg = (side ? x2 : x1) + (size_t)g * NPG * F_IN;
    const int* eib  = side ? ei2 : ei1;
    const int* srcg = eib + (size_t)g * EPG;
    const int* dstg = eib + N_EDGES + (size_t)g * EPG;
    const int nb = g * NPG;

    // ---- local CSR build ----
    if (tid < NPG) cnt[tid] = 0;
    __syncthreads();
#pragma unroll
    for (int it = 0; it < EPG / 512; ++it)
        atomicAdd(&cnt[dstg[it * 512 + tid] - nb], 1);
    __syncthreads();
    if (tid < NPG) dinv[tid] = rsqrtf((float)cnt[tid] + 1.0f);
    __syncthreads();
    for (int st = 1; st < NPG; st <<= 1) {       // Hillis-Steele inclusive scan
        int v = 0;
        if (tid < NPG && tid >= st) v = cnt[tid - st];
        __syncthreads();
        if (tid < NPG) cnt[tid] += v;
        __syncthreads();
    }
    if (tid < NPG) rowp[tid + 1] = cnt[tid];
    if (tid == 0) rowp[0] = 0;
    __syncthreads();
    if (tid < NPG) curs[tid] = rowp[tid];
    __syncthreads();
#pragma unroll
    for (int it = 0; it < EPG / 512; ++it) {
        const int e = it * 512 + tid;
        const int d = dstg[e] - nb;
        const int s = srcg[e] - nb;
        const int p = atomicAdd(&curs[d], 1);
        lsrc[p] = (unsigned char)s;
    }
    // ---- stage x as f16 [n][SP] into Q ----
#pragma unroll
    for (int it = 0; it < 4; ++it) {
        const int idx = (it * 512 + tid) * 4;
        const float4 v = *(const float4*)&xg[idx];
        const int n = idx >> 6, c = idx & 63;
        f16x4 o = {(f16)v.x, (f16)v.y, (f16)v.z, (f16)v.w};
        *(f16x4*)&Q[n * SP + c] = o;
    }
    __syncthreads();

    // layer 1: (A~ x) @ W1 + b1, relu
    agg_lds<F_IN, SP, SP, false, false>(Q, R, rowp, lsrc, dinv, nullptr, tid);  // a1 -> R
    __syncthreads();
    stage_wt<F_IN, F1, SP>(W1, Q, tid);                                         // Wt1 -> Q
    __syncthreads();
    mm_mfma<F_IN, F1, SP, SP, SP1, true, true>(R, Q, b1, P, tid);               // h1 -> P
    __syncthreads();
    // layer 2: A~ (h1 @ W2) + b2, relu
    stage_wt<F1, F2, SP1>(W2, Q, tid);                                          // Wt2 -> Q
    __syncthreads();
    mm_mfma<F1, F2, SP1, SP1, SP, false, false>(P, Q, nullptr, R, tid);         // t2 -> R
    __syncthreads();
    agg_lds<F2, SP, SP, true, true>(R, Q, rowp, lsrc, dinv, b2, tid);           // h2 -> Q
    __syncthreads();
    // layer 3: A~ (h2 @ W3) + b3
    stage_wt<F2, F3, SP>(W3, R, tid);                                           // Wt3 -> R[0:4608)
    __syncthreads();
    mm_mfma<F2, F3, SP, SP, SP3, false, false>(Q, R, nullptr, t3, tid);         // t3 -> R+4608
    __syncthreads();
    agg_out(t3, dtg + (size_t)(side * NGRAPH + g) * (F3 * NPG),
            rowp, lsrc, dinv, b3, tid);                                         // dt -> global
}

// ---- post kernel LDS pool ----
#define B_S1    0                      // f16 [32][132] = 8448
#define B_S2    8448                   // f16 [32][132] = 8448
#define B_LH    16896                  // ushort 512*17 = 17408
#define B_WL    34304                  // f32 1794 -> 7184
#define B_POOL  41488

__global__ __launch_bounds__(512) void post_kernel(
    const f16* __restrict__ dtg,
    const float* __restrict__ attW, const float* __restrict__ tW,
    const float* __restrict__ tblk, const float* __restrict__ tbias,
    const float* __restrict__ sW1, const float* __restrict__ sb1,
    const float* __restrict__ sW2, const float* __restrict__ sb2,
    float* __restrict__ outp) {
    __shared__ __align__(16) char pool[B_POOL];
    f16* s1T = (f16*)(pool + B_S1);
    f16* s2T = (f16*)(pool + B_S2);
    unsigned short* lhist = (unsigned short*)(pool + B_LH);
    float* wl   = (float*)(pool + B_WL);
    float* red  = wl;          // 16
    float* lohi = wl + 16;     // 2
    float* meanv= wl + 18;     // 64
    float* ctxv = wl + 82;     // 64
    float* ev   = wl + 146;    // 64
    float* feat = wl + 210;    // 32
    float* hv   = wl + 242;    // 16
    float* av   = wl + 258;    // 256
    float* pmean= wl + 514;    // 512
    float* ptens= wl + 1026;   // 512
    int*   bins2= (int*)(wl + 1538); // 256

    const int g = blockIdx.x;
    const int tid = threadIdx.x;
    const f16* dt0 = dtg + (size_t)g * (F3 * NPG);
    const f16* dt1 = dtg + (size_t)(NGRAPH + g) * (F3 * NPG);

    // stage dt tiles (linear [32][128] -> stride-132)
#pragma unroll
    for (int it = 0; it < 2; ++it) {
        const int i = (it * 512 + tid) * 4;
        const int c = i >> 7, n = i & 127;
        *(f16x4*)&s1T[c * XSH + n] = *(const f16x4*)&dt0[i];
        *(f16x4*)&s2T[c * XSH + n] = *(const f16x4*)&dt1[i];
    }
    for (int i = tid; i < 512 * 17 / 2; i += 512) ((unsigned int*)lhist)[i] = 0u;
    __syncthreads();

    // ---- scores once into registers: 4 n-rows x 8 m-cols per thread ----
    const int ny = tid >> 4, mx = tid & 15;
    const int n0 = ny * 4, m0 = mx * 8;
    float sc[4][8];
#pragma unroll
    for (int r = 0; r < 4; ++r)
#pragma unroll
        for (int m = 0; m < 8; ++m) sc[r][m] = 0.f;
#pragma unroll 4
    for (int k = 0; k < F3; ++k) {
        const f16x4 a4 = *(const f16x4*)&s1T[k * XSH + n0];
        const f16x4 b4 = *(const f16x4*)&s2T[k * XSH + m0];
        const f16x4 c4 = *(const f16x4*)&s2T[k * XSH + m0 + 4];
        float avr[4], bv[8];
#pragma unroll
        for (int r = 0; r < 4; ++r) avr[r] = (float)a4[r];
#pragma unroll
        for (int m = 0; m < 4; ++m) { bv[m] = (float)b4[m]; bv[4 + m] = (float)c4[m]; }
#pragma unroll
        for (int r = 0; r < 4; ++r)
#pragma unroll
            for (int m = 0; m < 8; ++m) sc[r][m] += avr[r] * bv[m];
    }
    // min/max (raw space; sigmoid monotone)
    float lmin = sc[0][0], lmax = sc[0][0];
#pragma unroll
    for (int r = 0; r < 4; ++r)
#pragma unroll
        for (int m = 0; m < 8; ++m) {
            lmin = fminf(lmin, sc[r][m]);
            lmax = fmaxf(lmax, sc[r][m]);
        }
    for (int off = 32; off; off >>= 1) {
        lmin = fminf(lmin, __shfl_down(lmin, off));
        lmax = fmaxf(lmax, __shfl_down(lmax, off));
    }
    const int wid = tid >> 6;
    if ((tid & 63) == 0) { red[wid] = lmin; red[8 + wid] = lmax; }
    __syncthreads();
    if (tid == 0) {
        float mn = red[0], mxv = red[8];
        for (int w = 1; w < 8; ++w) { mn = fminf(mn, red[w]); mxv = fmaxf(mxv, red[8 + w]); }
        lohi[0] = sigmoidf(mn);
        lohi[1] = sigmoidf(mxv);
    }
    __syncthreads();
    const float lo = lohi[0];
    const float denom = fmaxf(lohi[1] - lo, 1e-12f);

    // ---- histogram into per-thread private counters ----
    {
        unsigned short* lh = &lhist[tid * 17];
#pragma unroll
        for (int r = 0; r < 4; ++r)
#pragma unroll
            for (int m = 0; m < 8; ++m) {
                const float v = sigmoidf(sc[r][m]);
                int bidx = (int)floorf((v - lo) / denom * (float)BINS);
                bidx = min(max(bidx, 0), BINS - 1);
                lh[bidx]++;
            }
    }
    __syncthreads();
    if (tid < 256) {
        const int b = tid & 15, chunk = tid >> 4;
        int s = 0;
        for (int i = 0; i < 32; ++i) s += lhist[(chunk * 32 + i) * 17 + b];
        bins2[chunk * 16 + b] = s;
    }
    __syncthreads();

    // ---- attention pooling ----
    {
        const int col = tid & 63, chunk = tid >> 6;
        const f16* sT = (col < 32) ? &s1T[col * XSH] : &s2T[(col - 32) * XSH];
        float s = 0.f;
        const int nbs = chunk * 16;
        for (int n = 0; n < 16; ++n) s += (float)sT[nbs + n];
        pmean[chunk * 64 + col] = s;
    }
    __syncthreads();
    if (tid < 64) {
        float s = 0.f;
        for (int c = 0; c < 8; ++c) s += pmean[c * 64 + tid];
        meanv[tid] = s * (1.f / NPG);
    }
    __syncthreads();
    if (tid < 64) {
        const int c = tid & 31;
        const float* mv = &meanv[(tid >> 5) * 32];
        float acc = 0.f;
        for (int k = 0; k < F3; ++k) acc += mv[k] * attW[k * F3 + c];
        ctxv[tid] = tanhf(acc);
    }
    __syncthreads();
    if (tid < 256) {
        const int n = tid & 127, side = tid >> 7;
        const f16* sT = side ? s2T : s1T;
        const float* cx = &ctxv[side * 32];
        float acc = 0.f;
        for (int k = 0; k < F3; ++k) acc += (float)sT[k * XSH + n] * cx[k];
        av[tid] = sigmoidf(acc);
    }
    __syncthreads();
    {
        const int col = tid & 63, chunk = tid >> 6;
        const int side = col >> 5;
        const f16* sT = side ? &s2T[(col - 32) * XSH] : &s1T[col * XSH];
        const float* a = &av[side * 128];
        float s = 0.f;
        const int nbs = chunk * 16;
        for (int n = 0; n < 16; ++n) s += a[nbs + n] * (float)sT[nbs + n];
        pmean[chunk * 64 + col] = s;
    }
    __syncthreads();
    if (tid < 64) {
        float s = 0.f;
        for (int c = 0; c < 8; ++c) s += pmean[c * 64 + tid];
        ev[tid] = s;
    }
    __syncthreads();

    // ---- tensor network ----
    {
        const int k = tid & 15, i = tid >> 4;  // i in 0..31
        const float e1i = ev[i];
        float acc = 0.f;
        for (int j = 0; j < F3; ++j) acc += ev[32 + j] * tW[(i * F3 + j) * TN + k];
        ptens[i * 16 + k] = e1i * acc;
    }
    __syncthreads();
    if (tid < TN) {
        float acc = tbias[tid];
        for (int i = 0; i < 32; ++i) acc += ptens[i * 16 + tid];
        for (int i = 0; i < F3; ++i) acc += ev[i] * tblk[tid * 2 * F3 + i];
        for (int j = 0; j < F3; ++j) acc += ev[32 + j] * tblk[tid * 2 * F3 + F3 + j];
        feat[tid] = fmaxf(acc, 0.f);
    } else if (tid < TN + BINS) {
        const int b = tid - TN;
        int s = 0;
        for (int c = 0; c < 16; ++c) s += bins2[c * 16 + b];
        feat[tid] = (float)s * (1.f / (NPG * NPG));
    }
    __syncthreads();
    if (tid < 16) {
        float acc = sb1[tid];
        for (int i = 0; i < TN + BINS; ++i) acc += feat[i] * sW1[i * 16 + tid];
        hv[tid] = fmaxf(acc, 0.f);
    }
    __syncthreads();
    if (tid == 0) {
        float acc = sb2[0];
        for (int j = 0; j < 16; ++j) acc += hv[j] * sW2[j];
        outp[g] = sigmoidf(acc);
    }
}

// ---------------- launch ----------------
extern "C" void kernel_launch(void* const* d_in, const int* in_sizes, int n_in,
                              void* d_out, int out_size, void* d_ws, size_t ws_size,
                              hipStream_t stream) {
    const float* x1   = (const float*)d_in[0];
    const int*   ei1  = (const int*)d_in[1];
    const float* x2   = (const float*)d_in[3];
    const int*   ei2  = (const int*)d_in[4];
    const float* W1   = (const float*)d_in[6];
    const float* b1   = (const float*)d_in[7];
    const float* W2   = (const float*)d_in[8];
    const float* b2   = (const float*)d_in[9];
    const float* W3   = (const float*)d_in[10];
    const float* b3   = (const float*)d_in[11];
    const float* attW = (const float*)d_in[12];
    const float* tW   = (const float*)d_in[13];
    const float* tblk = (const float*)d_in[14];
    const float* tbias= (const float*)d_in[15];
    const float* sW1  = (const float*)d_in[16];
    const float* sb1  = (const float*)d_in[17];
    const float* sW2  = (const float*)d_in[18];
    const float* sb2  = (const float*)d_in[19];
    float* out = (float*)d_out;
    (void)in_sizes; (void)n_in; (void)out_size; (void)ws_size;

    f16* dtg = (f16*)d_ws;   // [2][256][32][128] f16 = 4MB

    gcn_kernel<<<NGRAPH * 2, 512, 0, stream>>>(x1, ei1, x2, ei2,
                                               W1, b1, W2, b2, W3, b3, dtg);
    post_kernel<<<NGRAPH, 512, 0, stream>>>(dtg, attW, tW, tblk, tbias,
                                            sW1, sb1, sW2, sb2, out);
}

// Round 9
// 35.517 us; speedup vs baseline: 30.8751x; 1.4502x over previous
//
#include <hip/hip_runtime.h>
#include <hip/hip_bf16.h>
#include <hip/hip_fp16.h>

// Problem constants (fixed by the reference harness)
#define N_NODES 32768
#define N_EDGES 524288
#define NGRAPH  256
#define NPG     128
#define EPG     2048     // edges per graph (DEG=16)
#define F_IN    64
#define F1      128
#define F2      64
#define F3      32
#define TN      16
#define BINS    16

typedef _Float16 f16;
typedef _Float16 f16x8 __attribute__((ext_vector_type(8)));
typedef float    f32x4 __attribute__((ext_vector_type(4)));

__device__ __forceinline__ float sigmoidf(float x) { return 1.f / (1.f + expf(-x)); }

// ---- LDS pool (bytes), 149504 total -> 1 block/CU, 8 waves ----
// R0: Acnt u32[128][68] == Amat f16[128][136]   (persist per side)
// R1: xT[64][136] -> h1[128][136]
// R2: W1T[128][72] -> h2[128][72]
// R3: out1[128][72] -> t2T[64][136] -> t3T[32][136] -> post smalls (f32)
// R4: W2T[64][136] -> lhist u16[512][17]
// R5: W3T[32][72]
// R6: dt f16[2][128][40]
// R7: dinv f32[128]
#define L_A    0
#define L_R1   34816
#define L_R2   69632
#define L_R3   88064
#define L_R4   106496
#define L_R5   123904
#define L_DT   128512
#define L_DINV 148992
#define POOLB  149504

#define SA  136   // Amat / xT / h1 / W2T / t2T / t3T stride (f16)
#define SB  72    // out1 / W1T / h2 / W3T stride
#define SD  40    // dt stride

// ---- generic MFMA matmul over LDS f16 tiles ----
// out[r][c] (or out[c][r] if TRANS) = sum_k A[r][k]*B^T[c][k] (+bias[c]) (relu)
// A: [128][AS], B: [N][BS] (transposed-B layout), M fixed at 128 (8 waves x 16 rows).
template<int N, int K, int AS, int BS, int OS, bool TRANS, bool RELU>
__device__ __forceinline__ void mfma_mm(const f16* __restrict__ A,
                                        const f16* __restrict__ B,
                                        const float* __restrict__ bias,
                                        f16* __restrict__ out, int tid) {
    const int wv = tid >> 6, lane = tid & 63;
    const int col = lane & 15, g = lane >> 4;
    const int rowa = wv * 16 + col;
    constexpr int NT = N / 16, KS = K / 32;
    f32x4 acc[NT];
#pragma unroll
    for (int nt = 0; nt < NT; ++nt) {
        const float b = bias ? bias[nt * 16 + col] : 0.f;
        acc[nt] = (f32x4){b, b, b, b};
    }
#pragma unroll
    for (int ks = 0; ks < KS; ++ks) {
        const f16x8 a = *(const f16x8*)&A[rowa * AS + ks * 32 + g * 8];
#pragma unroll
        for (int nt = 0; nt < NT; ++nt) {
            const f16x8 b = *(const f16x8*)&B[(nt * 16 + col) * BS + ks * 32 + g * 8];
            acc[nt] = __builtin_amdgcn_mfma_f32_16x16x32_f16(a, b, acc[nt], 0, 0, 0);
        }
    }
#pragma unroll
    for (int nt = 0; nt < NT; ++nt)
#pragma unroll
        for (int j = 0; j < 4; ++j) {
            float v = acc[nt][j];
            if (RELU) v = fmaxf(v, 0.f);
            const int r = wv * 16 + g * 4 + j, c = nt * 16 + col;
            if (TRANS) out[c * OS + r] = (f16)v;
            else       out[r * OS + c] = (f16)v;
        }
}

// ---- the whole network: one block per graph pair, one dispatch ----
__global__ __launch_bounds__(512, 1) void genn_all(
    const float* __restrict__ x1, const int* __restrict__ ei1,
    const float* __restrict__ x2, const int* __restrict__ ei2,
    const float* __restrict__ W1, const float* __restrict__ b1,
    const float* __restrict__ W2, const float* __restrict__ b2,
    const float* __restrict__ W3, const float* __restrict__ b3,
    const float* __restrict__ attW, const float* __restrict__ tW,
    const float* __restrict__ tblk, const float* __restrict__ tbias,
    const float* __restrict__ sW1, const float* __restrict__ sb1,
    const float* __restrict__ sW2, const float* __restrict__ sb2,
    float* __restrict__ outp) {
    __shared__ __align__(16) char pool[POOLB];
    unsigned int* Acnt = (unsigned int*)(pool + L_A);
    f16*   Amat = (f16*)(pool + L_A);
    f16*   dts  = (f16*)(pool + L_DT);
    float* dinv = (float*)(pool + L_DINV);

    const int g = blockIdx.x;
    const int tid = threadIdx.x;
    const int wv = tid >> 6, lane = tid & 63;

    for (int side = 0; side < 2; ++side) {
        const float* xg = (side ? x2 : x1) + (size_t)g * NPG * F_IN;
        const int* eib  = side ? ei2 : ei1;
        const int* srcg = eib + (size_t)g * EPG;
        const int* dstg = eib + N_EDGES + (size_t)g * EPG;
        const int nb = g * NPG;

        // ---- P0: zero Acnt (128*68 u32 = 2176 uint4) ----
        for (int i = tid; i < 2176; i += 512)
            ((uint4*)Acnt)[i] = make_uint4(0, 0, 0, 0);
        __syncthreads();

        // ---- P1: edge scatter (u16-packed counts) + stage xT + stage W's ----
#pragma unroll
        for (int it = 0; it < EPG / 512; ++it) {
            const int e = it * 512 + tid;
            const int d = dstg[e] - nb;
            const int s = srcg[e] - nb;
            atomicAdd(&Acnt[d * 68 + (s >> 1)], 1u << ((s & 1) << 4));
        }
        {
            f16* xT = (f16*)(pool + L_R1);
#pragma unroll
            for (int it = 0; it < 4; ++it) {
                const int idx = (it * 512 + tid) * 4;
                const float4 v = *(const float4*)&xg[idx];
                const int n = idx >> 6, c = idx & 63;
                xT[(c + 0) * SA + n] = (f16)v.x;
                xT[(c + 1) * SA + n] = (f16)v.y;
                xT[(c + 2) * SA + n] = (f16)v.z;
                xT[(c + 3) * SA + n] = (f16)v.w;
            }
            f16* W1T = (f16*)(pool + L_R2);
            for (int i = tid; i < F_IN * F1; i += 512)
                W1T[(i & 127) * SB + (i >> 7)] = (f16)W1[i];
            if (side == 0) {
                f16* W2T = (f16*)(pool + L_R4);
                for (int i = tid; i < F1 * F2; i += 512)
                    W2T[(i & 63) * SA + (i >> 6)] = (f16)W2[i];
                f16* W3T = (f16*)(pool + L_R5);
                for (int i = tid; i < F2 * F3; i += 512)
                    W3T[(i & 31) * SB + (i >> 5)] = (f16)W3[i];
            }
        }
        __syncthreads();

        // ---- P2: row sums -> dinv (4 lanes per row) ----
        {
            const int d = tid >> 2, q = tid & 3;
            unsigned int s = 0;
            const unsigned int* rp = &Acnt[d * 68 + q * 17];
            for (int j = 0; j < 17; ++j) {
                const unsigned int v = rp[j];
                s += (v & 0xffffu) + (v >> 16);
            }
            s += __shfl_down((int)s, 2);
            s += __shfl_down((int)s, 1);
            if (q == 0) dinv[d] = rsqrtf((float)s + 1.0f);
        }
        __syncthreads();

        // ---- P3: convert counts -> Amat f16 in place (+ self loop on diag) ----
        for (int i = tid; i < 8704; i += 512) {
            const int d = i / 68, w = i % 68;
            const unsigned int v = Acnt[i];
            const int s0 = 2 * w, s1 = 2 * w + 1;
            int c0 = v & 0xffffu, c1 = v >> 16;
            if (s0 == d) ++c0;
            if (s1 == d) ++c1;
            const float dd = dinv[d];
            const f16 f0 = (f16)((float)c0 * dinv[s0 & 127] * dd);
            const f16 f1 = (f16)((float)c1 * dinv[s1 & 127] * dd);
            unsigned int o;
            unsigned short u0 = __builtin_bit_cast(unsigned short, f0);
            unsigned short u1 = __builtin_bit_cast(unsigned short, f1);
            o = (unsigned int)u0 | ((unsigned int)u1 << 16);
            Acnt[i] = o;
        }
        __syncthreads();

        // ---- layers, all MFMA ----
        f16* xT   = (f16*)(pool + L_R1);
        f16* h1   = (f16*)(pool + L_R1);
        f16* W1T  = (f16*)(pool + L_R2);
        f16* h2   = (f16*)(pool + L_R2);
        f16* out1 = (f16*)(pool + L_R3);
        f16* t2T  = (f16*)(pool + L_R3);
        f16* t3T  = (f16*)(pool + L_R3);
        f16* W2T  = (f16*)(pool + L_R4);
        f16* W3T  = (f16*)(pool + L_R5);

        mfma_mm<64, 128, SA, SA, SB, false, false>(Amat, xT, nullptr, out1, tid);  // agg1
        __syncthreads();
        mfma_mm<128, 64, SB, SB, SA, false, true>(out1, W1T, b1, h1, tid);         // mm1
        __syncthreads();
        mfma_mm<64, 128, SA, SA, SA, true, false>(h1, W2T, nullptr, t2T, tid);     // mm2 (T)
        __syncthreads();
        mfma_mm<64, 128, SA, SA, SB, false, true>(Amat, t2T, b2, h2, tid);         // agg2
        __syncthreads();
        mfma_mm<32, 64, SB, SB, SA, true, false>(h2, W3T, nullptr, t3T, tid);      // mm3 (T)
        __syncthreads();
        mfma_mm<32, 128, SA, SA, SD, false, false>(Amat, t3T, b3,
                                                   dts + side * (NPG * SD), tid);  // agg3
        __syncthreads();
    }

    // ================= post phase (dt1/dt2 in LDS) =================
    unsigned short* lhist = (unsigned short*)(pool + L_R4);
    float* pf   = (float*)(pool + L_R3);
    float* red  = pf;          // 16
    float* lohi = pf + 16;     // 2
    float* meanv= pf + 18;     // 64
    float* ctxv = pf + 82;     // 64
    float* ev   = pf + 146;    // 64
    float* feat = pf + 210;    // 32
    float* hv   = pf + 242;    // 16
    float* av   = pf + 258;    // 256
    float* pmean= pf + 514;    // 512
    float* ptens= pf + 1026;   // 512
    int*   bins2= (int*)(pf + 1538); // 256
    const f16* d1 = dts;
    const f16* d2 = dts + NPG * SD;

    // ---- scores via MFMA: sc[n1][n2], K=32; each thread holds 32 scores ----
    const int col = lane & 15, gq = lane >> 4;
    const int rowa = wv * 16 + col;
    f32x4 acc[8];
#pragma unroll
    for (int nt = 0; nt < 8; ++nt) acc[nt] = (f32x4){0.f, 0.f, 0.f, 0.f};
    {
        const f16x8 a = *(const f16x8*)&d1[rowa * SD + gq * 8];
#pragma unroll
        for (int nt = 0; nt < 8; ++nt) {
            const f16x8 b = *(const f16x8*)&d2[(nt * 16 + col) * SD + gq * 8];
            acc[nt] = __builtin_amdgcn_mfma_f32_16x16x32_f16(a, b, acc[nt], 0, 0, 0);
        }
    }
    // zero private hist while scores are in flight
    for (int i = tid; i < 4352; i += 512) ((unsigned int*)lhist)[i] = 0u;
    // min/max
    float lmin = acc[0][0], lmax = acc[0][0];
#pragma unroll
    for (int nt = 0; nt < 8; ++nt)
#pragma unroll
        for (int j = 0; j < 4; ++j) {
            lmin = fminf(lmin, acc[nt][j]);
            lmax = fmaxf(lmax, acc[nt][j]);
        }
    for (int off = 32; off; off >>= 1) {
        lmin = fminf(lmin, __shfl_down(lmin, off));
        lmax = fmaxf(lmax, __shfl_down(lmax, off));
    }
    if (lane == 0) { red[wv] = lmin; red[8 + wv] = lmax; }
    __syncthreads();
    if (tid == 0) {
        float mn = red[0], mx = red[8];
        for (int w = 1; w < 8; ++w) { mn = fminf(mn, red[w]); mx = fmaxf(mx, red[8 + w]); }
        lohi[0] = sigmoidf(mn);
        lohi[1] = sigmoidf(mx);
    }
    __syncthreads();
    const float lo = lohi[0];
    const float denom = fmaxf(lohi[1] - lo, 1e-12f);

    // ---- histogram into per-thread private counters ----
    {
        unsigned short* lh = &lhist[tid * 17];
#pragma unroll
        for (int nt = 0; nt < 8; ++nt)
#pragma unroll
            for (int j = 0; j < 4; ++j) {
                const float v = sigmoidf(acc[nt][j]);
                int b = (int)floorf((v - lo) / denom * (float)BINS);
                b = min(max(b, 0), BINS - 1);
                lh[b]++;
            }
    }
    __syncthreads();
    if (tid < 256) {
        const int b = tid & 15, chunk = tid >> 4;
        int s = 0;
        for (int i = 0; i < 32; ++i) s += lhist[(chunk * 32 + i) * 17 + b];
        bins2[chunk * 16 + b] = s;
    }
    __syncthreads();

    // ---- attention pooling (dt is [n][c] stride SD) ----
    {
        const int cc = tid & 63, chunk = tid >> 6;
        const int side = cc >> 5, c = cc & 31;
        const f16* dp = dts + side * (NPG * SD);
        float s = 0.f;
        const int nbs = chunk * 16;
        for (int n = 0; n < 16; ++n) s += (float)dp[(nbs + n) * SD + c];
        pmean[chunk * 64 + cc] = s;
    }
    __syncthreads();
    if (tid < 64) {
        float s = 0.f;
        for (int c = 0; c < 8; ++c) s += pmean[c * 64 + tid];
        meanv[tid] = s * (1.f / NPG);
    }
    __syncthreads();
    if (tid < 64) {
        const int c = tid & 31;
        const float* mv = &meanv[(tid >> 5) * 32];
        float a = 0.f;
        for (int k = 0; k < F3; ++k) a += mv[k] * attW[k * F3 + c];
        ctxv[tid] = tanhf(a);
    }
    __syncthreads();
    if (tid < 256) {
        const int n = tid & 127, side = tid >> 7;
        const f16* dp = dts + side * (NPG * SD);
        const float* cx = &ctxv[side * 32];
        float a = 0.f;
        for (int k = 0; k < F3; ++k) a += (float)dp[n * SD + k] * cx[k];
        av[tid] = sigmoidf(a);
    }
    __syncthreads();
    {
        const int cc = tid & 63, chunk = tid >> 6;
        const int side = cc >> 5, c = cc & 31;
        const f16* dp = dts + side * (NPG * SD);
        const float* a = &av[side * 128];
        float s = 0.f;
        const int nbs = chunk * 16;
        for (int n = 0; n < 16; ++n) s += a[nbs + n] * (float)dp[(nbs + n) * SD + c];
        pmean[chunk * 64 + cc] = s;
    }
    __syncthreads();
    if (tid < 64) {
        float s = 0.f;
        for (int c = 0; c < 8; ++c) s += pmean[c * 64 + tid];
        ev[tid] = s;
    }
    __syncthreads();

    // ---- tensor network ----
    {
        const int k = tid & 15, i = tid >> 4;  // i in 0..31
        const float e1i = ev[i];
        float a = 0.f;
        for (int j = 0; j < F3; ++j) a += ev[32 + j] * tW[(i * F3 + j) * TN + k];
        ptens[i * 16 + k] = e1i * a;
    }
    __syncthreads();
    if (tid < TN) {
        float a = tbias[tid];
        for (int i = 0; i < 32; ++i) a += ptens[i * 16 + tid];
        for (int i = 0; i < F3; ++i) a += ev[i] * tblk[tid * 2 * F3 + i];
        for (int j = 0; j < F3; ++j) a += ev[32 + j] * tblk[tid * 2 * F3 + F3 + j];
        feat[tid] = fmaxf(a, 0.f);
    } else if (tid < TN + BINS) {
        const int b = tid - TN;
        int s = 0;
        for (int c = 0; c < 16; ++c) s += bins2[c * 16 + b];
        feat[tid] = (float)s * (1.f / (NPG * NPG));
    }
    __syncthreads();
    if (tid < 16) {
        float a = sb1[tid];
        for (int i = 0; i < TN + BINS; ++i) a += feat[i] * sW1[i * 16 + tid];
        hv[tid] = fmaxf(a, 0.f);
    }
    __syncthreads();
    if (tid == 0) {
        float a = sb2[0];
        for (int j = 0; j < 16; ++j) a += hv[j] * sW2[j];
        outp[g] = sigmoidf(a);
    }
}

// ---------------- launch ----------------
extern "C" void kernel_launch(void* const* d_in, const int* in_sizes, int n_in,
                              void* d_out, int out_size, void* d_ws, size_t ws_size,
                              hipStream_t stream) {
    const float* x1   = (const float*)d_in[0];
    const int*   ei1  = (const int*)d_in[1];
    const float* x2   = (const float*)d_in[3];
    const int*   ei2  = (const int*)d_in[4];
    const float* W1   = (const float*)d_in[6];
    const float* b1   = (const float*)d_in[7];
    const float* W2   = (const float*)d_in[8];
    const float* b2   = (const float*)d_in[9];
    const float* W3   = (const float*)d_in[10];
    const float* b3   = (const float*)d_in[11];
    const float* attW = (const float*)d_in[12];
    const float* tW   = (const float*)d_in[13];
    const float* tblk = (const float*)d_in[14];
    const float* tbias= (const float*)d_in[15];
    const float* sW1  = (const float*)d_in[16];
    const float* sb1  = (const float*)d_in[17];
    const float* sW2  = (const float*)d_in[18];
    const float* sb2  = (const float*)d_in[19];
    float* out = (float*)d_out;
    (void)in_sizes; (void)n_in; (void)out_size; (void)d_ws; (void)ws_size;

    genn_all<<<NGRAPH, 512, 0, stream>>>(x1, ei1, x2, ei2,
                                         W1, b1, W2, b2, W3, b3,
                                         attW, tW, tblk, tbias,
                                         sW1, sb1, sW2, sb2, out);
}

// Round 10
// 34.719 us; speedup vs baseline: 31.5844x; 1.0230x over previous
//
#include <hip/hip_runtime.h>
#include <hip/hip_bf16.h>
#include <hip/hip_fp16.h>

// Problem constants (fixed by the reference harness)
#define N_NODES 32768
#define N_EDGES 524288
#define NGRAPH  256
#define NPG     128
#define EPG     2048     // edges per graph (DEG=16)
#define F_IN    64
#define F1      128
#define F2      64
#define F3      32
#define TN      16
#define BINS    16

typedef _Float16 f16;
typedef _Float16 f16x4 __attribute__((ext_vector_type(4)));
typedef _Float16 f16x8 __attribute__((ext_vector_type(8)));
typedef float    f32x4 __attribute__((ext_vector_type(4)));

__device__ __forceinline__ float sigmoidf(float x) { return 1.f / (1.f + expf(-x)); }

// ---- LDS pool (bytes), 149504 total -> 1 block/CU, 16 waves ----
#define L_A    0        // Acnt u32[128][68] == Amat f16[128][136] (per side)
#define L_R1   34816    // xT[64][136] -> h1[128][136]
#define L_R2   69632    // W1T[128][72] -> h2[128][72]
#define L_R3   88064    // out1[128][72] -> t2T[64][136] -> t3T[32][136] -> post smalls
#define L_R4   106496   // W2T[64][136] -> lhist u8[1024][17]
#define L_R5   123904   // W3T[32][72]
#define L_DT   128512   // dt f16[2][128][40]
#define L_DINV 148992   // dinv f32[128]
#define POOLB  149504

#define SA  136   // Amat / xT / h1 / W2T / t2T / t3T stride (f16)
#define SB  72    // out1 / W1T / h2 / W3T stride
#define SD  40    // dt stride

// ---- generic MFMA matmul over LDS f16 tiles; 16 waves = 8 M-strips x 2 N-halves ----
// out[r][c] (or out[c][r] if TRANS) = sum_k A[r][k]*B^T[c][k] (+bias[c]) (relu)
template<int N, int K, int AS, int BS, int OS, bool TRANS, bool RELU>
__device__ __forceinline__ void mfma_mm(const f16* __restrict__ A,
                                        const f16* __restrict__ B,
                                        const float* __restrict__ bias,
                                        f16* __restrict__ out, int tid) {
    const int w = tid >> 6, lane = tid & 63;
    const int col = lane & 15, g = lane >> 4;
    const int strip = w & 7, nh = w >> 3;
    const int rowa = strip * 16 + col;
    constexpr int NT = N / 16, KS = K / 32, NT2 = NT / 2;
    f32x4 acc[NT2];
#pragma unroll
    for (int nt = 0; nt < NT2; ++nt) {
        const float b = bias ? bias[(nh * NT2 + nt) * 16 + col] : 0.f;
        acc[nt] = (f32x4){b, b, b, b};
    }
#pragma unroll
    for (int ks = 0; ks < KS; ++ks) {
        const f16x8 a = *(const f16x8*)&A[rowa * AS + ks * 32 + g * 8];
#pragma unroll
        for (int nt = 0; nt < NT2; ++nt) {
            const f16x8 b = *(const f16x8*)&B[((nh * NT2 + nt) * 16 + col) * BS + ks * 32 + g * 8];
            acc[nt] = __builtin_amdgcn_mfma_f32_16x16x32_f16(a, b, acc[nt], 0, 0, 0);
        }
    }
#pragma unroll
    for (int nt = 0; nt < NT2; ++nt) {
        const int c = (nh * NT2 + nt) * 16 + col;
        if (TRANS) {
            f16x4 o;
#pragma unroll
            for (int j = 0; j < 4; ++j) {
                float v = acc[nt][j];
                if (RELU) v = fmaxf(v, 0.f);
                o[j] = (f16)v;
            }
            *(f16x4*)&out[c * OS + strip * 16 + g * 4] = o;
        } else {
#pragma unroll
            for (int j = 0; j < 4; ++j) {
                float v = acc[nt][j];
                if (RELU) v = fmaxf(v, 0.f);
                out[(strip * 16 + g * 4 + j) * OS + c] = (f16)v;
            }
        }
    }
}

// ---- the whole network: one block per graph pair, one dispatch, 1024 threads ----
__global__ __launch_bounds__(1024, 4) void genn_all(
    const float* __restrict__ x1, const int* __restrict__ ei1,
    const float* __restrict__ x2, const int* __restrict__ ei2,
    const float* __restrict__ W1, const float* __restrict__ b1,
    const float* __restrict__ W2, const float* __restrict__ b2,
    const float* __restrict__ W3, const float* __restrict__ b3,
    const float* __restrict__ attW, const float* __restrict__ tW,
    const float* __restrict__ tblk, const float* __restrict__ tbias,
    const float* __restrict__ sW1, const float* __restrict__ sb1,
    const float* __restrict__ sW2, const float* __restrict__ sb2,
    float* __restrict__ outp) {
    __shared__ __align__(16) char pool[POOLB];
    unsigned int* Acnt = (unsigned int*)(pool + L_A);
    f16*   Amat = (f16*)(pool + L_A);
    f16*   dts  = (f16*)(pool + L_DT);
    float* dinv = (float*)(pool + L_DINV);

    const int g = blockIdx.x;
    const int tid = threadIdx.x;
    const int wv = tid >> 6, lane = tid & 63;

    for (int side = 0; side < 2; ++side) {
        const float* xg = (side ? x2 : x1) + (size_t)g * NPG * F_IN;
        const int* eib  = side ? ei2 : ei1;
        const int* srcg = eib + (size_t)g * EPG;
        const int* dstg = eib + N_EDGES + (size_t)g * EPG;
        const int nb = g * NPG;

        // ---- P0: zero Acnt (128*68 u32 = 2176 uint4) ----
        for (int i = tid; i < 2176; i += 1024)
            ((uint4*)Acnt)[i] = make_uint4(0, 0, 0, 0);
        __syncthreads();

        // ---- P1: edge scatter (u16-packed counts) + stage xT + stage W's ----
#pragma unroll
        for (int it = 0; it < EPG / 1024; ++it) {
            const int e = it * 1024 + tid;
            const int d = dstg[e] - nb;
            const int s = srcg[e] - nb;
            atomicAdd(&Acnt[d * 68 + (s >> 1)], 1u << ((s & 1) << 4));
        }
        {
            f16* xT = (f16*)(pool + L_R1);
#pragma unroll
            for (int it = 0; it < 2; ++it) {
                const int idx = (it * 1024 + tid) * 4;
                const float4 v = *(const float4*)&xg[idx];
                const int n = idx >> 6, c = idx & 63;
                xT[(c + 0) * SA + n] = (f16)v.x;
                xT[(c + 1) * SA + n] = (f16)v.y;
                xT[(c + 2) * SA + n] = (f16)v.z;
                xT[(c + 3) * SA + n] = (f16)v.w;
            }
            f16* W1T = (f16*)(pool + L_R2);
            for (int i = tid; i < F_IN * F1; i += 1024)
                W1T[(i & 127) * SB + (i >> 7)] = (f16)W1[i];
            if (side == 0) {
                f16* W2T = (f16*)(pool + L_R4);
                for (int i = tid; i < F1 * F2; i += 1024)
                    W2T[(i & 63) * SA + (i >> 6)] = (f16)W2[i];
                f16* W3T = (f16*)(pool + L_R5);
                for (int i = tid; i < F2 * F3; i += 1024)
                    W3T[(i & 31) * SB + (i >> 5)] = (f16)W3[i];
            }
        }
        __syncthreads();

        // ---- P2: row sums -> dinv (4 lanes per row; first 512 threads) ----
        if (tid < 512) {
            const int d = tid >> 2, q = tid & 3;
            unsigned int s = 0;
            const unsigned int* rp = &Acnt[d * 68 + q * 17];
            for (int j = 0; j < 17; ++j) {
                const unsigned int v = rp[j];
                s += (v & 0xffffu) + (v >> 16);
            }
            s += __shfl_down((int)s, 2);
            s += __shfl_down((int)s, 1);
            if (q == 0) dinv[d] = rsqrtf((float)s + 1.0f);
        }
        __syncthreads();

        // ---- P3: convert counts -> Amat f16 in place (+ self loop on diag) ----
        for (int i = tid; i < 8704; i += 1024) {
            const int d = i / 68, w = i % 68;
            const unsigned int v = Acnt[i];
            const int s0 = 2 * w, s1 = 2 * w + 1;
            int c0 = v & 0xffffu, c1 = v >> 16;
            if (s0 == d) ++c0;
            if (s1 == d) ++c1;
            const float dd = dinv[d];
            const f16 f0 = (f16)((float)c0 * dinv[s0 & 127] * dd);
            const f16 f1 = (f16)((float)c1 * dinv[s1 & 127] * dd);
            unsigned short u0 = __builtin_bit_cast(unsigned short, f0);
            unsigned short u1 = __builtin_bit_cast(unsigned short, f1);
            Acnt[i] = (unsigned int)u0 | ((unsigned int)u1 << 16);
        }
        __syncthreads();

        // ---- layers, all MFMA ----
        f16* xT   = (f16*)(pool + L_R1);
        f16* h1   = (f16*)(pool + L_R1);
        f16* W1T  = (f16*)(pool + L_R2);
        f16* h2   = (f16*)(pool + L_R2);
        f16* out1 = (f16*)(pool + L_R3);
        f16* t2T  = (f16*)(pool + L_R3);
        f16* t3T  = (f16*)(pool + L_R3);
        f16* W2T  = (f16*)(pool + L_R4);
        f16* W3T  = (f16*)(pool + L_R5);

        mfma_mm<64, 128, SA, SA, SB, false, false>(Amat, xT, nullptr, out1, tid);  // agg1
        __syncthreads();
        mfma_mm<128, 64, SB, SB, SA, false, true>(out1, W1T, b1, h1, tid);         // mm1
        __syncthreads();
        mfma_mm<64, 128, SA, SA, SA, true, false>(h1, W2T, nullptr, t2T, tid);     // mm2 (T)
        __syncthreads();
        mfma_mm<64, 128, SA, SA, SB, false, true>(Amat, t2T, b2, h2, tid);         // agg2
        __syncthreads();
        mfma_mm<32, 64, SB, SB, SA, true, false>(h2, W3T, nullptr, t3T, tid);      // mm3 (T)
        __syncthreads();
        mfma_mm<32, 128, SA, SA, SD, false, false>(Amat, t3T, b3,
                                                   dts + side * (NPG * SD), tid);  // agg3
        __syncthreads();
    }

    // ================= post phase (dt1/dt2 in LDS) =================
    unsigned char* lhist = (unsigned char*)(pool + L_R4);   // [1024][17] u8
    float* pf   = (float*)(pool + L_R3);
    float* red  = pf;           // 32
    float* lohi = pf + 32;      // 2
    float* meanv= pf + 34;      // 64
    float* ctxv = pf + 98;      // 64
    float* ev   = pf + 162;     // 64
    float* feat = pf + 226;     // 32
    float* hv   = pf + 258;     // 16
    float* thr  = pf + 274;     // 15
    float* av   = pf + 290;     // 256
    float* pmean= pf + 546;     // 1024
    float* ptens= pf + 1570;    // 512
    int*   bins2= (int*)(pf + 2082); // 256
    const f16* d1 = dts;
    const f16* d2 = dts + NPG * SD;

    // ---- scores via MFMA: sc[n1][n2], K=32; 16 scores per thread ----
    const int col = lane & 15, gq = lane >> 4;
    const int strip = wv & 7, nh = wv >> 3;
    const int rowa = strip * 16 + col;
    f32x4 acc[4];
#pragma unroll
    for (int nt = 0; nt < 4; ++nt) acc[nt] = (f32x4){0.f, 0.f, 0.f, 0.f};
    {
        const f16x8 a = *(const f16x8*)&d1[rowa * SD + gq * 8];
#pragma unroll
        for (int nt = 0; nt < 4; ++nt) {
            const f16x8 b = *(const f16x8*)&d2[((nh * 4 + nt) * 16 + col) * SD + gq * 8];
            acc[nt] = __builtin_amdgcn_mfma_f32_16x16x32_f16(a, b, acc[nt], 0, 0, 0);
        }
    }
    // zero private hist while scores are in flight
    for (int i = tid; i < 4352; i += 1024) ((unsigned int*)lhist)[i] = 0u;
    // min/max (raw space)
    float lmin = acc[0][0], lmax = acc[0][0];
#pragma unroll
    for (int nt = 0; nt < 4; ++nt)
#pragma unroll
        for (int j = 0; j < 4; ++j) {
            lmin = fminf(lmin, acc[nt][j]);
            lmax = fmaxf(lmax, acc[nt][j]);
        }
    for (int off = 32; off; off >>= 1) {
        lmin = fminf(lmin, __shfl_down(lmin, off));
        lmax = fmaxf(lmax, __shfl_down(lmax, off));
    }
    if (lane == 0) { red[wv] = lmin; red[16 + wv] = lmax; }
    __syncthreads();
    if (tid == 0) {
        float mn = red[0], mx = red[16];
        for (int w = 1; w < 16; ++w) { mn = fminf(mn, red[w]); mx = fmaxf(mx, red[16 + w]); }
        const float los = sigmoidf(mn);
        const float den = fmaxf(sigmoidf(mx) - los, 1e-12f);
        lohi[0] = los;
        lohi[1] = den;
    }
    __syncthreads();
    // raw-space bin thresholds: t_k = logit(lo + k*den/16), k=1..15
    if (tid < 15) {
        const float p = lohi[0] + (float)(tid + 1) * lohi[1] * (1.f / 16.f);
        thr[tid] = logf(p / (1.f - p));
    }
    __syncthreads();

    // ---- histogram via threshold counting (no per-score sigmoid) ----
    {
        unsigned char* lh = &lhist[tid * 17];
#pragma unroll
        for (int nt = 0; nt < 4; ++nt)
#pragma unroll
            for (int j = 0; j < 4; ++j) {
                const float x = acc[nt][j];
                int b = 0;
#pragma unroll
                for (int k = 0; k < 15; ++k) b += (x >= thr[k]) ? 1 : 0;
                lh[b]++;
            }
    }
    __syncthreads();
    if (tid < 256) {
        const int b = tid & 15, chunk = tid >> 4;   // 16 chunks x 64 rows
        int s = 0;
        for (int i = 0; i < 64; ++i) s += lhist[(chunk * 64 + i) * 17 + b];
        bins2[chunk * 16 + b] = s;
    }
    __syncthreads();

    // ---- attention pooling (dt is [n][c] stride SD) ----
    {
        const int cc = tid & 63, chunk = tid >> 6;  // 16 chunks x 8 nodes
        const int side = cc >> 5, c = cc & 31;
        const f16* dp = dts + side * (NPG * SD);
        float s = 0.f;
        const int nbs = chunk * 8;
        for (int n = 0; n < 8; ++n) s += (float)dp[(nbs + n) * SD + c];
        pmean[chunk * 64 + cc] = s;
    }
    __syncthreads();
    if (tid < 64) {
        float s = 0.f;
        for (int c = 0; c < 16; ++c) s += pmean[c * 64 + tid];
        meanv[tid] = s * (1.f / NPG);
    }
    __syncthreads();
    if (tid < 64) {
        const int c = tid & 31;
        const float* mv = &meanv[(tid >> 5) * 32];
        float a = 0.f;
        for (int k = 0; k < F3; ++k) a += mv[k] * attW[k * F3 + c];
        ctxv[tid] = tanhf(a);
    }
    __syncthreads();
    if (tid < 256) {
        const int n = tid & 127, side = tid >> 7;
        const f16* dp = dts + side * (NPG * SD);
        const float* cx = &ctxv[side * 32];
        float a = 0.f;
        for (int k = 0; k < F3; ++k) a += (float)dp[n * SD + k] * cx[k];
        av[tid] = sigmoidf(a);
    }
    __syncthreads();
    {
        const int cc = tid & 63, chunk = tid >> 6;
        const int side = cc >> 5, c = cc & 31;
        const f16* dp = dts + side * (NPG * SD);
        const float* a = &av[side * 128];
        float s = 0.f;
        const int nbs = chunk * 8;
        for (int n = 0; n < 8; ++n) s += a[nbs + n] * (float)dp[(nbs + n) * SD + c];
        pmean[chunk * 64 + cc] = s;
    }
    __syncthreads();
    if (tid < 64) {
        float s = 0.f;
        for (int c = 0; c < 16; ++c) s += pmean[c * 64 + tid];
        ev[tid] = s;
    }
    __syncthreads();

    // ---- tensor network ----
    if (tid < 512) {
        const int k = tid & 15, i = tid >> 4;  // i in 0..31
        const float e1i = ev[i];
        float a = 0.f;
        for (int j = 0; j < F3; ++j) a += ev[32 + j] * tW[(i * F3 + j) * TN + k];
        ptens[i * 16 + k] = e1i * a;
    }
    __syncthreads();
    if (tid < TN) {
        float a = tbias[tid];
        for (int i = 0; i < 32; ++i) a += ptens[i * 16 + tid];
        for (int i = 0; i < F3; ++i) a += ev[i] * tblk[tid * 2 * F3 + i];
        for (int j = 0; j < F3; ++j) a += ev[32 + j] * tblk[tid * 2 * F3 + F3 + j];
        feat[tid] = fmaxf(a, 0.f);
    } else if (tid < TN + BINS) {
        const int b = tid - TN;
        int s = 0;
        for (int c = 0; c < 16; ++c) s += bins2[c * 16 + b];
        feat[tid] = (float)s * (1.f / (NPG * NPG));
    }
    __syncthreads();
    if (tid < 16) {
        float a = sb1[tid];
        for (int i = 0; i < TN + BINS; ++i) a += feat[i] * sW1[i * 16 + tid];
        hv[tid] = fmaxf(a, 0.f);
    }
    __syncthreads();
    if (tid == 0) {
        float a = sb2[0];
        for (int j = 0; j < 16; ++j) a += hv[j] * sW2[j];
        outp[g] = sigmoidf(a);
    }
}

// ---------------- launch ----------------
extern "C" void kernel_launch(void* const* d_in, const int* in_sizes, int n_in,
                              void* d_out, int out_size, void* d_ws, size_t ws_size,
                              hipStream_t stream) {
    const float* x1   = (const float*)d_in[0];
    const int*   ei1  = (const int*)d_in[1];
    const float* x2   = (const float*)d_in[3];
    const int*   ei2  = (const int*)d_in[4];
    const float* W1   = (const float*)d_in[6];
    const float* b1   = (const float*)d_in[7];
    const float* W2   = (const float*)d_in[8];
    const float* b2   = (const float*)d_in[9];
    const float* W3   = (const float*)d_in[10];
    const float* b3   = (const float*)d_in[11];
    const float* attW = (const float*)d_in[12];
    const float* tW   = (const float*)d_in[13];
    const float* tblk = (const float*)d_in[14];
    const float* tbias= (const float*)d_in[15];
    const float* sW1  = (const float*)d_in[16];
    const float* sb1  = (const float*)d_in[17];
    const float* sW2  = (const float*)d_in[18];
    const float* sb2  = (const float*)d_in[19];
    float* out = (float*)d_out;
    (void)in_sizes; (void)n_in; (void)out_size; (void)d_ws; (void)ws_size;

    genn_all<<<NGRAPH, 1024, 0, stream>>>(x1, ei1, x2, ei2,
                                          W1, b1, W2, b2, W3, b3,
                                          attW, tW, tblk, tbias,
                                          sW1, sb1, sW2, sb2, out);
}